// Round 5
// baseline (2374.378 us; speedup 1.0000x reference)
//
#include <hip/hip_runtime.h>

#define ALPHA 0.3f
#define BNEPS 1e-3f

typedef __attribute__((ext_vector_type(8))) short bf16x8;
typedef __attribute__((ext_vector_type(4))) float f32x4;
typedef __attribute__((ext_vector_type(16))) float f32x16;

__device__ __forceinline__ short f2bf(float x){
    unsigned u = __float_as_uint(x);
    unsigned r = (u + 0x7FFFu + ((u >> 16) & 1u)) >> 16;   // RNE
    return (short)r;
}
__device__ __forceinline__ float bf2f(short s){
    return __uint_as_float(((unsigned)(unsigned short)s) << 16);
}

// ---------------- routing: counting sort of samples by class ----------------
__global__ void sort_k(const int* __restrict__ labels, int* __restrict__ order){
    __shared__ int cnt[10], offs[10];
    int tid = threadIdx.x;
    if (tid < 10) cnt[tid] = 0;
    __syncthreads();
    int lab = labels[tid];
    atomicAdd(&cnt[lab], 1);
    __syncthreads();
    if (tid == 0){
        int s = 0;
        for (int c = 0; c < 10; c++){ offs[c] = s; s += cnt[c]; }
    }
    __syncthreads();
    int pos = atomicAdd(&offs[lab], 1);
    order[pos] = tid;
}

// ---------------- weight prep: fp32 -> bf16 hi/lo, B-fragment layout, fully coalesced ----
// W1T: [ct (250)][chunk=ci/8 (40)][co (256)][ci%8]   ci in [0,320), >=306 zero
// W2T: [ct][chunk=ci/8 (32)][co (128)][ci%8]
#define N1 20480000   // 250*40*256*8
#define N2 8192000    // 250*32*128*8
#define T1 2560000    // 250*40*256
__global__ __launch_bounds__(256) void prep_k(const float* __restrict__ K1, const float* __restrict__ K2,
                       short* __restrict__ w1h, short* __restrict__ w1l,
                       short* __restrict__ w2h, short* __restrict__ w2l){
    int t = blockIdx.x * 256 + threadIdx.x;
    if (t < T1){
        int co = t & 255;
        int ch = (t >> 8) % 40;
        int ct = (t >> 8) / 40;
        bf16x8 h, l;
        #pragma unroll
        for (int j = 0; j < 8; j++){
            int ci = ch*8 + j;
            float w = (ci < 306) ? K1[((size_t)ct*306 + ci)*256 + co] : 0.f;
            short hh = f2bf(w);
            h[j] = hh;
            l[j] = f2bf(w - bf2f(hh));
        }
        size_t dst = (size_t)t * 8;
        *(bf16x8*)&w1h[dst] = h;
        *(bf16x8*)&w1l[dst] = l;
    } else {
        int tt = t - T1;
        int co = tt & 127;
        int ch = (tt >> 7) & 31;
        int ct = tt >> 12;
        bf16x8 h, l;
        #pragma unroll
        for (int j = 0; j < 8; j++){
            int ci = ch*8 + j;
            float w = K2[((size_t)ct*256 + ci)*128 + co];
            short hh = f2bf(w);
            h[j] = hh;
            l[j] = f2bf(w - bf2f(hh));
        }
        size_t dst = (size_t)tt * 8;
        *(bf16x8*)&w2h[dst] = h;
        *(bf16x8*)&w2l[dst] = l;
    }
}

// ---------------- dense 150->12544 + BN1 + LReLU -> xg hi/lo bf16 in ws ----------------
__global__ __launch_bounds__(256)
void dense_k(const float* __restrict__ noise, const int* __restrict__ labels,
             const float* __restrict__ emb,   const float* __restrict__ Wd,
             const float* __restrict__ g1, const float* __restrict__ b1,
             const float* __restrict__ m1, const float* __restrict__ v1,
             short* __restrict__ xgH, short* __restrict__ xgL){
    __shared__ float xs[16][152];
    const int tid = threadIdx.x;
    const int q  = blockIdx.x % 49;
    const int st = blockIdx.x / 49;
    for (int i = tid; i < 16*150; i += 256){
        int ss = i / 150, k = i % 150;
        int b = st*16 + ss;
        xs[ss][k] = (k < 100) ? noise[b*100 + k] : emb[labels[b]*50 + (k-100)];
    }
    __syncthreads();
    const int co = tid;
    const int j = q*256 + co;
    float acc[16];
    #pragma unroll
    for (int ss = 0; ss < 16; ss++) acc[ss] = 0.f;
    #pragma unroll 2
    for (int k = 0; k < 150; k++){
        float w = Wd[k*12544 + j];
        #pragma unroll
        for (int ss = 0; ss < 16; ss++)
            acc[ss] += xs[ss][k] * w;
    }
    float sc = g1[j] * rsqrtf(v1[j] + BNEPS);
    float mm = m1[j], bb = b1[j];
    #pragma unroll
    for (int ss = 0; ss < 16; ss++){
        float y = (acc[ss] - mm)*sc + bb;
        y = (y >= 0.f) ? y : ALPHA*y;
        short h = f2bf(y), l = f2bf(y - bf2f(h));
        size_t o = ((size_t)(st*16 + ss)*49 + q)*320 + co;
        xgH[o] = h; xgL[o] = l;
    }
    {
        int ss = tid >> 4, cg = tid & 15;
        #pragma unroll
        for (int cj = 0; cj < 4; cj++){
            int col = 256 + cg*4 + cj;
            float v = (col < 306) ? xs[ss][100 + col - 256] : 0.f;
            short h = f2bf(v), l = f2bf(v - bf2f(h));
            size_t o = ((size_t)(st*16 + ss)*49 + q)*320 + col;
            xgH[o] = h; xgL[o] = l;
        }
    }
}

// ---------------- main: 1 sample/block, 512 threads (8 waves), 2 blocks/CU ----------------
// conv1: 8 waves = nq (32-col strip); mi=2, ni=1, FULL K (20 ks steps) -> no K-split,
//        no LDS scratch, no cross-wave combine. acc = 32 VGPR/thread.
// conv2: 8 waves = (parity, nh col-half); mi=2, ni=2 (R1-proven shape).
// conv3: f32 through LDS in two 64-channel passes (h2a 196x68 f32, 16B-aligned rows).
__global__ __launch_bounds__(512, 4)
void main_k(const int* __restrict__ labels, const int* __restrict__ order,
            const short* __restrict__ xgH, const short* __restrict__ xgL,
            const short* __restrict__ w1h, const short* __restrict__ w1l,
            const short* __restrict__ w2h, const short* __restrict__ w2l,
            const float* __restrict__ G1, const float* __restrict__ B1,
            const float* __restrict__ M1, const float* __restrict__ V1,
            const float* __restrict__ G2, const float* __restrict__ B2,
            const float* __restrict__ M2, const float* __restrict__ V2,
            const float* __restrict__ K3, float* __restrict__ out){
    // smem overlay (66,112 B = 33,056 shorts):
    //  conv1-in : plane h at h*16400 shorts, rows 50 x stride 328 (row 49 = zeros)
    //  conv2-in : plane h at h*13200 shorts, rows 50 x stride 264 (row 49 = zeros)
    //  conv3    : h2a (196*68 f32 = 53,312 B) + wk3 (3200 f32 at float 13328)
    __shared__ __align__(16) short smem[33056];
    __shared__ int binfo[2];
    const int tid = threadIdx.x;
    const int idx = ((blockIdx.x & 7) << 6) | (blockIdx.x >> 3);   // XCD swizzle, 512 blocks
    if (tid == 0){
        int b = order[idx];
        binfo[0] = b;
        binfo[1] = labels[b];
    }
    {   // zero LDS (padding rows rely on this)
        uint4 z; z.x = z.y = z.z = z.w = 0;
        uint4* p = (uint4*)smem;
        for (int i = tid; i < 4132; i += 512) p[i] = z;
    }
    __syncthreads();
    const int b = binfo[0], c = binfo[1];
    // copy xcat rows (h,q): 98 rows x 40 uint4
    for (int i = tid; i < 3920; i += 512){
        int t = i % 40, w = i / 40;
        int q = w % 49, h = w / 49;
        const short* src = (h ? xgL : xgH) + ((size_t)b*49 + q)*320;
        *(uint4*)&smem[h*16400 + q*328 + t*8] = *(const uint4*)&src[t*8];
    }
    __syncthreads();

    const int lane = tid & 63, wid = tid >> 6;
    const int l31 = lane & 31, half = lane >> 5;

    // ================= conv1: 7x7x306 -> 7x7x256 (s=1, pads 2,2), full-K per wave ==========
    {
        const int co1 = wid*32 + l31;                  // 8 waves x 32 cols = 256
        f32x16 acc1[2];
        #pragma unroll
        for (int mi = 0; mi < 2; mi++)
            #pragma unroll
            for (int r = 0; r < 16; r++) acc1[mi][r] = 0.f;
        int py[2], px[2], pok[2];
        #pragma unroll
        for (int mi = 0; mi < 2; mi++){
            int p = mi*32 + l31;
            py[mi] = p/7; px[mi] = p%7; pok[mi] = (p < 49);
        }
        #pragma unroll 1
        for (int tap = 0; tap < 25; tap++){
            int ky = tap/5, kx = tap%5;
            int aoff[2];
            #pragma unroll
            for (int mi = 0; mi < 2; mi++){
                int iy = py[mi] + ky - 2, ix = px[mi] + kx - 2;
                bool ok = pok[mi] & (iy >= 0) & (iy < 7) & (ix >= 0) & (ix < 7);
                int q = ok ? iy*7 + ix : 49;             // row 49 = zeros
                aoff[mi] = q*328 + half*8;
            }
            size_t boff = ((size_t)(c*25 + tap))*81920 + ((size_t)(half*256 + co1))*8;
            const short* pbh = w1h + boff;
            const short* pbl = w1l + boff;
            #pragma unroll 2
            for (int ks = 0; ks < 20; ks++){
                bf16x8 Bh = *(const bf16x8*)&pbh[ks*4096];   // chunk = ks*2 + half
                bf16x8 Bl = *(const bf16x8*)&pbl[ks*4096];
                bf16x8 Ah[2], Al[2];
                #pragma unroll
                for (int mi = 0; mi < 2; mi++){
                    Ah[mi] = *(const bf16x8*)&smem[aoff[mi] + ks*16];
                    Al[mi] = *(const bf16x8*)&smem[aoff[mi] + 16400 + ks*16];
                }
                __builtin_amdgcn_s_setprio(1);
                #pragma unroll
                for (int mi = 0; mi < 2; mi++){
                    acc1[mi] = __builtin_amdgcn_mfma_f32_32x32x16_bf16(Ah[mi], Bh, acc1[mi], 0, 0, 0);
                    acc1[mi] = __builtin_amdgcn_mfma_f32_32x32x16_bf16(Ah[mi], Bl, acc1[mi], 0, 0, 0);
                    acc1[mi] = __builtin_amdgcn_mfma_f32_32x32x16_bf16(Al[mi], Bh, acc1[mi], 0, 0, 0);
                }
                __builtin_amdgcn_s_setprio(0);
            }
        }
        __syncthreads();   // all conv1 LDS reads complete -> region becomes conv2 input
        // epilogue: BN + LReLU -> conv2-in (hi/lo), one col per thread
        float sc1 = G1[c*256 + co1] * rsqrtf(V1[c*256 + co1] + BNEPS);
        float mm1 = M1[c*256 + co1], bb1 = B1[c*256 + co1];
        short* yh = smem;
        short* yl = smem + 13200;
        #pragma unroll
        for (int mi = 0; mi < 2; mi++)
            #pragma unroll
            for (int r = 0; r < 16; r++){
                int p = mi*32 + (r & 3) + 8*(r >> 2) + 4*half;
                if (p < 49){
                    float y = (acc1[mi][r] - mm1)*sc1 + bb1;
                    y = (y >= 0.f) ? y : ALPHA*y;
                    short h = f2bf(y), l = f2bf(y - bf2f(h));
                    int o = p*264 + co1;
                    yh[o] = h; yl[o] = l;
                }
            }
        // zero row 49 of both conv2-in planes (528 shorts)
        for (int j = tid; j < 528; j += 512){
            int pl = j / 264, col = j % 264;
            smem[pl*13200 + 49*264 + col] = 0;
        }
    }
    __syncthreads();

    // ================= conv2: 7x7x256 -> 14x14x128 (s=2, pads 3,2), parity split =================
    f32x16 acc2[2][2];
    int pi, pj, nh;
    {
        const int par = wid & 3; nh = wid >> 2;
        pi = par >> 1; pj = par & 1;
        #pragma unroll
        for (int mi = 0; mi < 2; mi++)
            #pragma unroll
            for (int ni = 0; ni < 2; ni++)
                #pragma unroll
                for (int r = 0; r < 16; r++) acc2[mi][ni][r] = 0.f;
        int py[2], px[2], pok[2];
        #pragma unroll
        for (int mi = 0; mi < 2; mi++){
            int p = mi*32 + l31;
            py[mi] = p/7; px[mi] = p%7; pok[mi] = (p < 49);
        }
        const int nky = pi ? 3 : 2, kyb = pi ? 0 : 1;
        const int nkx = pj ? 3 : 2, kxb = pj ? 0 : 1;
        #pragma unroll 1
        for (int ty = 0; ty < nky; ty++){
            int ky = kyb + 2*ty;
            int dy = (pi + ky - 3) / 2;
            #pragma unroll 1
            for (int tx = 0; tx < nkx; tx++){
                int kx = kxb + 2*tx;
                int dx = (pj + kx - 3) / 2;
                int tap = ky*5 + kx;
                int aoff[2];
                #pragma unroll
                for (int mi = 0; mi < 2; mi++){
                    int u = py[mi] + dy, v = px[mi] + dx;
                    bool ok = pok[mi] & (u >= 0) & (u < 7) & (v >= 0) & (v < 7);
                    int q = ok ? u*7 + v : 49;
                    aoff[mi] = q*264 + half*8;
                }
                size_t tapbase = ((size_t)(c*25 + tap))*32768;   // 32*128*8
                const short *pbh[2], *pbl[2];
                #pragma unroll
                for (int ni = 0; ni < 2; ni++){
                    int co = nh*64 + ni*32 + l31;
                    size_t off = tapbase + ((size_t)(half*128 + co))*8;
                    pbh[ni] = w2h + off; pbl[ni] = w2l + off;
                }
                #pragma unroll 2
                for (int ks = 0; ks < 16; ks++){
                    bf16x8 Ah[2], Al[2], Bh[2], Bl[2];
                    #pragma unroll
                    for (int mi = 0; mi < 2; mi++){
                        Ah[mi] = *(const bf16x8*)&smem[aoff[mi] + ks*16];
                        Al[mi] = *(const bf16x8*)&smem[aoff[mi] + 13200 + ks*16];
                    }
                    #pragma unroll
                    for (int ni = 0; ni < 2; ni++){
                        Bh[ni] = *(const bf16x8*)&pbh[ni][ks*2048];
                        Bl[ni] = *(const bf16x8*)&pbl[ni][ks*2048];
                    }
                    __builtin_amdgcn_s_setprio(1);
                    #pragma unroll
                    for (int mi = 0; mi < 2; mi++)
                        #pragma unroll
                        for (int ni = 0; ni < 2; ni++){
                            acc2[mi][ni] = __builtin_amdgcn_mfma_f32_32x32x16_bf16(Ah[mi], Bh[ni], acc2[mi][ni], 0, 0, 0);
                            acc2[mi][ni] = __builtin_amdgcn_mfma_f32_32x32x16_bf16(Ah[mi], Bl[ni], acc2[mi][ni], 0, 0, 0);
                            acc2[mi][ni] = __builtin_amdgcn_mfma_f32_32x32x16_bf16(Al[mi], Bh[ni], acc2[mi][ni], 0, 0, 0);
                        }
                    __builtin_amdgcn_s_setprio(0);
                }
            }
        }
    }
    __syncthreads();   // all conv2 LDS reads complete; smem free

    // ================= conv2 epilogue + conv3 in two 64-channel passes =================
    float sc2[2], mm2[2], bb2[2];
    #pragma unroll
    for (int ni = 0; ni < 2; ni++){
        int co = nh*64 + ni*32 + l31;
        sc2[ni] = G2[c*128 + co] * rsqrtf(V2[c*128 + co] + BNEPS);
        mm2[ni] = M2[c*128 + co];
        bb2[ni] = B2[c*128 + co];
    }
    float* h2a = (float*)smem;             // 196 x 68 f32 (53,312 B), rows 16B-aligned
    float* wk3 = (float*)smem + 13328;     // 3200 f32 (12,800 B)
    // stage conv3 weights + write channel-half 0 (nh==0 waves: conv2 cols 0..63)
    for (int i = tid; i < 3200; i += 512) wk3[i] = K3[c*3200 + i];
    if (nh == 0){
        #pragma unroll
        for (int mi = 0; mi < 2; mi++)
            #pragma unroll
            for (int ni = 0; ni < 2; ni++)
                #pragma unroll
                for (int r = 0; r < 16; r++){
                    int p = mi*32 + (r & 3) + 8*(r >> 2) + 4*half;
                    if (p < 49){
                        int oy = p / 7, ox = p % 7;
                        int q2 = (2*oy + pi)*14 + (2*ox + pj);
                        float y = (acc2[mi][ni][r] - mm2[ni])*sc2[ni] + bb2[ni];
                        y = (y >= 0.f) ? y : ALPHA*y;
                        h2a[q2*68 + ni*32 + l31] = y;
                    }
                }
    }
    __syncthreads();
    // conv3: 14x14x128 -> 28x28x1, s=2, pads (3,2), tanh; channel halves in two passes
    float a3_0 = 0.f, a3_1 = 0.f;
    const int p3a = tid, p3b = tid + 512;
    {   // pass 0: channels 0..63
        #pragma unroll 1
        for (int rep = 0; rep < 2; rep++){
            int p3 = rep ? p3b : p3a;
            if (p3 < 784){
                int oi = p3 / 28, oj = p3 % 28;
                float a = 0.f;
                #pragma unroll
                for (int ky = 0; ky < 5; ky++){
                    int t = oi + ky - 3;
                    if (t < 0 || (t & 1) || t >= 28) continue;
                    int u = t >> 1;
                    #pragma unroll
                    for (int kx = 0; kx < 5; kx++){
                        int ss2 = oj + kx - 3;
                        if (ss2 < 0 || (ss2 & 1) || ss2 >= 28) continue;
                        int v = ss2 >> 1;
                        const float* xr = &h2a[(u*14 + v)*68];
                        const float* w = &wk3[(ky*5 + kx)*128];
                        #pragma unroll
                        for (int cc = 0; cc < 16; cc++){
                            float4 xv = *(const float4*)&xr[4*cc];
                            float4 wv = *(const float4*)&w[4*cc];
                            a += xv.x*wv.x + xv.y*wv.y + xv.z*wv.z + xv.w*wv.w;
                        }
                    }
                }
                if (rep) a3_1 += a; else a3_0 += a;
            }
        }
    }
    __syncthreads();
    // write channel-half 1 (nh==1 waves: conv2 cols 64..127)
    if (nh == 1){
        #pragma unroll
        for (int mi = 0; mi < 2; mi++)
            #pragma unroll
            for (int ni = 0; ni < 2; ni++)
                #pragma unroll
                for (int r = 0; r < 16; r++){
                    int p = mi*32 + (r & 3) + 8*(r >> 2) + 4*half;
                    if (p < 49){
                        int oy = p / 7, ox = p % 7;
                        int q2 = (2*oy + pi)*14 + (2*ox + pj);
                        float y = (acc2[mi][ni][r] - mm2[ni])*sc2[ni] + bb2[ni];
                        y = (y >= 0.f) ? y : ALPHA*y;
                        h2a[q2*68 + ni*32 + l31] = y;
                    }
                }
    }
    __syncthreads();
    {   // pass 1: channels 64..127
        #pragma unroll 1
        for (int rep = 0; rep < 2; rep++){
            int p3 = rep ? p3b : p3a;
            if (p3 < 784){
                int oi = p3 / 28, oj = p3 % 28;
                float a = 0.f;
                #pragma unroll
                for (int ky = 0; ky < 5; ky++){
                    int t = oi + ky - 3;
                    if (t < 0 || (t & 1) || t >= 28) continue;
                    int u = t >> 1;
                    #pragma unroll
                    for (int kx = 0; kx < 5; kx++){
                        int ss2 = oj + kx - 3;
                        if (ss2 < 0 || (ss2 & 1) || ss2 >= 28) continue;
                        int v = ss2 >> 1;
                        const float* xr = &h2a[(u*14 + v)*68];
                        const float* w = &wk3[(ky*5 + kx)*128 + 64];
                        #pragma unroll
                        for (int cc = 0; cc < 16; cc++){
                            float4 xv = *(const float4*)&xr[4*cc];
                            float4 wv = *(const float4*)&w[4*cc];
                            a += xv.x*wv.x + xv.y*wv.y + xv.z*wv.z + xv.w*wv.w;
                        }
                    }
                }
                if (rep) a3_1 += a; else a3_0 += a;
            }
        }
    }
    if (p3a < 784) out[b*784 + p3a] = tanhf(a3_0);
    if (p3b < 784) out[b*784 + p3b] = tanhf(a3_1);
}

// =======================================================================================
// Fallback path (verified R5 kernel) — used when ws_size is too small for the MFMA path.
// =======================================================================================
#define NOISE 100
#define EMB   50
#define CIN1  306
#define S1    52

template<int PH>
__device__ __forceinline__ void conv1_full(const float* __restrict__ xt1, float* __restrict__ xt2,
                                           const float* __restrict__ wbase,
                                           float sc, float mm, float bb, int co){
    constexpr int OY0 = PH ? 4 : 0;
    constexpr int NOY = PH ? 3 : 4;
    float acc[NOY*7];
    #pragma unroll
    for (int i = 0; i < NOY*7; i++) acc[i] = 0.f;
    #pragma unroll 1
    for (int ci = 0; ci < CIN1; ci++){
        float xr[49];
        #pragma unroll
        for (int r = 0; r < 12; r++) *(float4*)&xr[4*r] = *(const float4*)&xt1[ci*S1 + 4*r];
        xr[48] = xt1[ci*S1 + 48];
        const float* wci = wbase + ci*256;
        #pragma unroll
        for (int ky = 0; ky < 5; ky++)
            #pragma unroll
            for (int kx = 0; kx < 5; kx++){
                float w = wci[(ky*5 + kx)*CIN1*256];
                #pragma unroll
                for (int oy = OY0; oy < OY0 + NOY; oy++){
                    int iy = oy + ky - 2;
                    if (iy < 0 || iy >= 7) continue;
                    #pragma unroll
                    for (int ox = 0; ox < 7; ox++){
                        int ix = ox + kx - 2;
                        if (ix < 0 || ix >= 7) continue;
                        acc[(oy - OY0)*7 + ox] += xr[iy*7 + ix] * w;
                    }
                }
            }
    }
    #pragma unroll
    for (int i = 0; i < NOY*7; i++){
        float y = (acc[i] - mm)*sc + bb;
        xt2[co*S1 + OY0*7 + i] = (y >= 0.f) ? y : ALPHA*y;
    }
}

template<int Q>
__device__ __forceinline__ void conv2_full(const float* __restrict__ xt2, float* __restrict__ xt3,
                                           const float* __restrict__ wbase,
                                           float sc, float mm, float bb, int co){
    float acc[49];
    #pragma unroll
    for (int i = 0; i < 49; i++) acc[i] = 0.f;
    #pragma unroll 1
    for (int ci = 0; ci < 256; ci++){
        float xr[49];
        #pragma unroll
        for (int r = 0; r < 12; r++) *(float4*)&xr[4*r] = *(const float4*)&xt2[ci*S1 + 4*r];
        xr[48] = xt2[ci*S1 + 48];
        const float* wci = wbase + ci*128;
        #pragma unroll
        for (int ky = 0; ky < 5; ky++)
            #pragma unroll
            for (int kx = 0; kx < 5; kx++){
                float w = wci[(ky*5 + kx)*256*128];
                #pragma unroll
                for (int ii = 0; ii < 49; ii++){
                    int p2 = Q*49 + ii;
                    int i = p2 / 14, j = p2 % 14;
                    int t = i + ky - 3, s = j + kx - 3;
                    if (t < 0 || (t & 1) || t >= 14) continue;
                    if (s < 0 || (s & 1) || s >= 14) continue;
                    acc[ii] += xr[(t >> 1)*7 + (s >> 1)] * w;
                }
            }
    }
    #pragma unroll
    for (int ii = 0; ii < 49; ii++){
        int p2 = Q*49 + ii;
        float y = (acc[ii] - mm)*sc + bb;
        xt3[p2*132 + co] = (y >= 0.f) ? y : ALPHA*y;
    }
}

__global__ __launch_bounds__(512, 2)
void fused_k(const float* __restrict__ noise, const int* __restrict__ labels,
             const float* __restrict__ emb,   const float* __restrict__ Wd,
             const float* __restrict__ g1,    const float* __restrict__ b1,
             const float* __restrict__ m1,    const float* __restrict__ v1,
             const float* __restrict__ K1,
             const float* __restrict__ G1, const float* __restrict__ B1,
             const float* __restrict__ M1, const float* __restrict__ V1,
             const float* __restrict__ K2,
             const float* __restrict__ G2, const float* __restrict__ B2,
             const float* __restrict__ M2, const float* __restrict__ V2,
             const float* __restrict__ K3,
             const int* __restrict__ order,
             float* __restrict__ out){
    __shared__ __align__(16) unsigned char smem[53248 + 103488];
    __shared__ float xin[152];
    float* xt2 = (float*)smem;
    float* wk  = (float*)smem;
    float* xt1 = (float*)(smem + 53248);
    float* xt3 = (float*)(smem + 53248);

    const int tid = threadIdx.x;
    const int idx = ((blockIdx.x & 7) << 6) | (blockIdx.x >> 3);
    const int b = order[idx];
    const int c = labels[b];

    if (tid < 150)
        xin[tid] = (tid < NOISE) ? noise[b*NOISE + tid] : emb[c*EMB + (tid - NOISE)];
    __syncthreads();
    {
        const int co = tid & 255;
        const int p0 = (tid >> 8) * 24;
        float acc[25];
        #pragma unroll
        for (int i = 0; i < 25; i++) acc[i] = 0.f;
        #pragma unroll 1
        for (int k = 0; k < 150; k++){
            float x = xin[k];
            const float* wr = Wd + k*12544 + p0*256 + co;
            #pragma unroll
            for (int i = 0; i < 25; i++) acc[i] += x * wr[i*256];
        }
        #pragma unroll
        for (int i = 0; i < 25; i++){
            int j = (p0 + i)*256 + co;
            float sc = g1[j] * rsqrtf(v1[j] + BNEPS);
            float y = (acc[i] - m1[j])*sc + b1[j];
            y = (y >= 0.f) ? y : ALPHA*y;
            xt1[co*S1 + p0 + i] = y;
        }
        if (tid < EMB){
            float v = xin[NOISE + tid];
            #pragma unroll
            for (int p = 0; p < 49; p++) xt1[(256 + tid)*S1 + p] = v;
        }
    }
    __syncthreads();
    {
        const int co = tid & 255;
        const int ph = tid >> 8;
        const float* wbase = K1 + (size_t)c*25*CIN1*256 + co;
        float sc = G1[c*256 + co] * rsqrtf(V1[c*256 + co] + BNEPS);
        float mm = M1[c*256 + co], bb = B1[c*256 + co];
        if (ph == 0) conv1_full<0>(xt1, xt2, wbase, sc, mm, bb, co);
        else         conv1_full<1>(xt1, xt2, wbase, sc, mm, bb, co);
    }
    __syncthreads();
    {
        const int co = tid & 127;
        const int q  = tid >> 7;
        const float* wbase = K2 + (size_t)c*25*256*128 + co;
        float sc = G2[c*128 + co] * rsqrtf(V2[c*128 + co] + BNEPS);
        float mm = M2[c*128 + co], bb = B2[c*128 + co];
        switch (q){
            case 0: conv2_full<0>(xt2, xt3, wbase, sc, mm, bb, co); break;
            case 1: conv2_full<1>(xt2, xt3, wbase, sc, mm, bb, co); break;
            case 2: conv2_full<2>(xt2, xt3, wbase, sc, mm, bb, co); break;
            default:conv2_full<3>(xt2, xt3, wbase, sc, mm, bb, co); break;
        }
    }
    __syncthreads();
    for (int i = tid; i < 3200; i += 512) wk[i] = K3[c*3200 + i];
    __syncthreads();
    #pragma unroll 1
    for (int rep = 0; rep < 2; rep++){
        int p3 = tid + rep*512;
        if (p3 < 784){
            int i = p3 / 28, j = p3 - (p3/28)*28;
            float acc = 0.f;
            #pragma unroll
            for (int ky = 0; ky < 5; ky++){
                int t = i + ky - 3;
                if (t < 0 || (t & 1) || t >= 28) continue;
                int u = t >> 1;
                #pragma unroll
                for (int kx = 0; kx < 5; kx++){
                    int s = j + kx - 3;
                    if (s < 0 || (s & 1) || s >= 28) continue;
                    int v = s >> 1;
                    const float* xr = &xt3[(u*14 + v)*132];
                    const float* w = &wk[(ky*5 + kx)*128];
                    #pragma unroll
                    for (int cc = 0; cc < 32; cc++){
                        float4 xv = *(const float4*)&xr[4*cc];
                        float4 wv = *(const float4*)&w[4*cc];
                        acc += xv.x*wv.x + xv.y*wv.y + xv.z*wv.z + xv.w*wv.w;
                    }
                }
            }
            out[b*784 + p3] = tanhf(acc);
        }
    }
}

extern "C" void kernel_launch(void* const* d_in, const int* in_sizes, int n_in,
                              void* d_out, int out_size, void* d_ws, size_t ws_size,
                              hipStream_t stream){
    const float* noise = (const float*)d_in[0];
    const int*   labels= (const int*)  d_in[1];
    const float* emb   = (const float*)d_in[2];
    const float* Wd    = (const float*)d_in[3];
    const float* g1    = (const float*)d_in[4];
    const float* b1    = (const float*)d_in[5];
    const float* m1    = (const float*)d_in[6];
    const float* v1    = (const float*)d_in[7];
    const float* K1    = (const float*)d_in[8];
    const float* G1    = (const float*)d_in[9];
    const float* B1    = (const float*)d_in[10];
    const float* M1    = (const float*)d_in[11];
    const float* V1    = (const float*)d_in[12];
    const float* K2    = (const float*)d_in[13];
    const float* G2    = (const float*)d_in[14];
    const float* B2    = (const float*)d_in[15];
    const float* M2    = (const float*)d_in[16];
    const float* V2    = (const float*)d_in[17];
    const float* K3    = (const float*)d_in[18];
    float* outp = (float*)d_out;

    const size_t NEED = 4096 + 2*(size_t)N1*2 + 2*(size_t)N2*2 + 2*(size_t)512*49*320*2;
    int* order = (int*)d_ws;

    if (ws_size >= NEED){
        short* w1h = (short*)((char*)d_ws + 4096);
        short* w1l = w1h + N1;
        short* w2h = w1l + N1;
        short* w2l = w2h + N2;
        short* xgH = w2l + N2;
        short* xgL = xgH + (size_t)512*49*320;
        sort_k <<<1, 512, 0, stream>>>(labels, order);
        prep_k <<<(T1 + N2/8 + 255)/256, 256, 0, stream>>>(K1, K2, w1h, w1l, w2h, w2l);
        dense_k<<<49*32, 256, 0, stream>>>(noise, labels, emb, Wd, g1, b1, m1, v1, xgH, xgL);
        main_k <<<512, 512, 0, stream>>>(labels, order, xgH, xgL, w1h, w1l, w2h, w2l,
                                         G1, B1, M1, V1, G2, B2, M2, V2, K3, outp);
    } else {
        // fallback: verified R5 path (needs only 2 KB ws)
        sort_k <<<1, 512, 0, stream>>>(labels, order);
        fused_k<<<512, 512, 0, stream>>>(noise, labels, emb, Wd, g1, b1, m1, v1,
                                         K1, G1, B1, M1, V1,
                                         K2, G2, B2, M2, V2, K3, order, outp);
    }
}

// Round 6
// 748.849 us; speedup vs baseline: 3.1707x; 3.1707x over previous
//
#include <hip/hip_runtime.h>

#define ALPHA 0.3f
#define BNEPS 1e-3f

typedef __attribute__((ext_vector_type(8))) short bf16x8;
typedef __attribute__((ext_vector_type(4))) float f32x4;

__device__ __forceinline__ short f2bf(float x){
    unsigned u = __float_as_uint(x);
    unsigned r = (u + 0x7FFFu + ((u >> 16) & 1u)) >> 16;   // RNE
    return (short)r;
}
__device__ __forceinline__ float bf2f(short s){
    return __uint_as_float(((unsigned)(unsigned short)s) << 16);
}

#define N1 20480000   // 250*40*256*8
#define N2 8192000    // 250*32*128*8
#define T1 2560000    // 250*40*256
#define PREP_BLKS 14000   // (T1 + N2/8)/256
#define DENSE_BLKS 1568   // 49*32

// ---------------- routing: counting sort of samples by class (512-thread, fallback) ----
__global__ void sort_k(const int* __restrict__ labels, int* __restrict__ order){
    __shared__ int cnt[10], offs[10];
    int tid = threadIdx.x;
    if (tid < 10) cnt[tid] = 0;
    __syncthreads();
    int lab = labels[tid];
    atomicAdd(&cnt[lab], 1);
    __syncthreads();
    if (tid == 0){
        int s = 0;
        for (int c = 0; c < 10; c++){ offs[c] = s; s += cnt[c]; }
    }
    __syncthreads();
    int pos = atomicAdd(&offs[lab], 1);
    order[pos] = tid;
}

// ---------------- fused aux kernel: sort (blk 0) + dense (blks 1..1568) + prep (rest) ----
// prep: fp32 -> bf16 hi/lo, B-fragment layout.
//   W1T: [ct (250)][chunk=ci/8 (40)][co (256)][ci%8]   ci in [0,320), >=306 zero
//   W2T: [ct][chunk=ci/8 (32)][co (128)][ci%8]
// dense: 150->12544 + BN1 + LReLU -> xg hi/lo bf16.
__global__ __launch_bounds__(256)
void aux_k(const float* __restrict__ noise, const int* __restrict__ labels,
           const float* __restrict__ emb,   const float* __restrict__ Wd,
           const float* __restrict__ g1, const float* __restrict__ b1,
           const float* __restrict__ m1, const float* __restrict__ v1,
           const float* __restrict__ K1, const float* __restrict__ K2,
           short* __restrict__ w1h, short* __restrict__ w1l,
           short* __restrict__ w2h, short* __restrict__ w2l,
           short* __restrict__ xgH, short* __restrict__ xgL,
           int* __restrict__ order){
    const int bid = blockIdx.x;
    const int tid = threadIdx.x;

    if (bid == 0){
        // ---- counting sort of 512 labels with 256 threads ----
        __shared__ int cnt[10], offs[10];
        if (tid < 10) cnt[tid] = 0;
        __syncthreads();
        int l0 = labels[tid], l1 = labels[tid + 256];
        atomicAdd(&cnt[l0], 1);
        atomicAdd(&cnt[l1], 1);
        __syncthreads();
        if (tid == 0){
            int s = 0;
            for (int c = 0; c < 10; c++){ offs[c] = s; s += cnt[c]; }
        }
        __syncthreads();
        int p0 = atomicAdd(&offs[l0], 1);
        order[p0] = tid;
        int p1 = atomicAdd(&offs[l1], 1);
        order[p1] = tid + 256;
        return;
    }

    if (bid <= DENSE_BLKS){
        // ---- dense: one (q, 16-sample tile) per block ----
        __shared__ float xs[16][152];
        const int b2 = bid - 1;
        const int q  = b2 % 49;
        const int st = b2 / 49;
        for (int i = tid; i < 16*150; i += 256){
            int ss = i / 150, k = i % 150;
            int b = st*16 + ss;
            xs[ss][k] = (k < 100) ? noise[b*100 + k] : emb[labels[b]*50 + (k-100)];
        }
        __syncthreads();
        const int co = tid;
        const int j = q*256 + co;
        float acc[16];
        #pragma unroll
        for (int ss = 0; ss < 16; ss++) acc[ss] = 0.f;
        #pragma unroll 2
        for (int k = 0; k < 150; k++){
            float w = Wd[k*12544 + j];
            #pragma unroll
            for (int ss = 0; ss < 16; ss++)
                acc[ss] += xs[ss][k] * w;
        }
        float sc = g1[j] * rsqrtf(v1[j] + BNEPS);
        float mm = m1[j], bb = b1[j];
        #pragma unroll
        for (int ss = 0; ss < 16; ss++){
            float y = (acc[ss] - mm)*sc + bb;
            y = (y >= 0.f) ? y : ALPHA*y;
            short h = f2bf(y), l = f2bf(y - bf2f(h));
            size_t o = ((size_t)(st*16 + ss)*49 + q)*320 + co;
            xgH[o] = h; xgL[o] = l;
        }
        {
            int ss = tid >> 4, cg = tid & 15;
            #pragma unroll
            for (int cj = 0; cj < 4; cj++){
                int col = 256 + cg*4 + cj;
                float v = (col < 306) ? xs[ss][100 + col - 256] : 0.f;
                short h = f2bf(v), l = f2bf(v - bf2f(h));
                size_t o = ((size_t)(st*16 + ss)*49 + q)*320 + col;
                xgH[o] = h; xgL[o] = l;
            }
        }
        return;
    }

    // ---- prep ----
    int t = (bid - 1 - DENSE_BLKS) * 256 + tid;
    if (t < T1){
        int co = t & 255;
        int ch = (t >> 8) % 40;
        int ct = (t >> 8) / 40;
        bf16x8 h, l;
        #pragma unroll
        for (int j = 0; j < 8; j++){
            int ci = ch*8 + j;
            float w = (ci < 306) ? K1[((size_t)ct*306 + ci)*256 + co] : 0.f;
            short hh = f2bf(w);
            h[j] = hh;
            l[j] = f2bf(w - bf2f(hh));
        }
        size_t dst = (size_t)t * 8;
        *(bf16x8*)&w1h[dst] = h;
        *(bf16x8*)&w1l[dst] = l;
    } else {
        int tt = t - T1;
        int co = tt & 127;
        int ch = (tt >> 7) & 31;
        int ct = tt >> 12;
        bf16x8 h, l;
        #pragma unroll
        for (int j = 0; j < 8; j++){
            int ci = ch*8 + j;
            float w = K2[((size_t)ct*256 + ci)*128 + co];
            short hh = f2bf(w);
            h[j] = hh;
            l[j] = f2bf(w - bf2f(hh));
        }
        size_t dst = (size_t)tt * 8;
        *(bf16x8*)&w2h[dst] = h;
        *(bf16x8*)&w2l[dst] = l;
    }
}

// ---------------- main: conv1 + conv2 (MFMA hi/lo) + conv3 (VALU), 2 samples/block ----------------
// 1024 threads = 16 waves -> 4 waves/SIMD at 1 block/CU (latency hiding).  [R1-verified, 606 us]
__global__ __launch_bounds__(1024, 1)
void main_k(const int* __restrict__ labels, const int* __restrict__ order,
            const short* __restrict__ xgH, const short* __restrict__ xgL,
            const short* __restrict__ w1h, const short* __restrict__ w1l,
            const short* __restrict__ w2h, const short* __restrict__ w2l,
            const float* __restrict__ G1, const float* __restrict__ B1,
            const float* __restrict__ M1, const float* __restrict__ V1,
            const float* __restrict__ G2, const float* __restrict__ B2,
            const float* __restrict__ M2, const float* __restrict__ V2,
            const float* __restrict__ K3, float* __restrict__ out){
    __shared__ __align__(16) short smem[65600];          // 131,200 B
    __shared__ int binfo[4];
    const int tid = threadIdx.x;
    const int idx = ((blockIdx.x & 7) << 5) | (blockIdx.x >> 3);   // XCD swizzle, 256 blocks
    if (tid < 2){
        int b = order[2*idx + tid];
        binfo[tid] = b;
        binfo[2 + tid] = labels[b];
    }
    {   // zero LDS (padding rows rely on this)
        uint4 z; z.x = z.y = z.z = z.w = 0;
        uint4* p = (uint4*)smem;
        for (int i = tid; i < 8200; i += 1024) p[i] = z;
    }
    __syncthreads();
    // copy xcat rows (s,h,q): 196 rows x 40 uint4
    for (int i = tid; i < 7840; i += 1024){
        int t = i % 40, w = i / 40;
        int q = w % 49, sh = w / 49;
        int s = sh >> 1, h = sh & 1;
        const short* src = (h ? xgL : xgH) + ((size_t)binfo[s]*49 + q)*320;
        *(uint4*)&smem[sh*16400 + q*328 + t*8] = *(const uint4*)&src[t*8];
    }
    __syncthreads();

    const int lane = tid & 63, wid = tid >> 6;
    const int l31 = lane & 31, half = lane >> 5;
    typedef __attribute__((ext_vector_type(16))) float f32x16;

    // ================= conv1: 7x7x306 -> 7x7x256 (s=1, pads 2,2), 32x32x16 MFMA =================
    {
        const int s = wid & 1, kv = (wid >> 1) & 1, nq = wid >> 2;   // nq 0..3
        const int c = binfo[2 + s];
        const short* xh = smem + (s*2 + 0)*16400;
        const short* xl = smem + (s*2 + 1)*16400;
        const int kvb = kv*160;
        f32x16 acc[2][2];
        #pragma unroll
        for (int mi = 0; mi < 2; mi++)
            #pragma unroll
            for (int ni = 0; ni < 2; ni++)
                #pragma unroll
                for (int r = 0; r < 16; r++) acc[mi][ni][r] = 0.f;
        int py[2], px[2], pok[2];
        #pragma unroll
        for (int mi = 0; mi < 2; mi++){
            int p = mi*32 + l31;
            py[mi] = p/7; px[mi] = p%7; pok[mi] = (p < 49);
        }
        #pragma unroll 1
        for (int tap = 0; tap < 25; tap++){
            int ky = tap/5, kx = tap%5;
            int aoff[2];
            #pragma unroll
            for (int mi = 0; mi < 2; mi++){
                int iy = py[mi] + ky - 2, ix = px[mi] + kx - 2;
                bool ok = pok[mi] & (iy >= 0) & (iy < 7) & (ix >= 0) & (ix < 7);
                int q = ok ? iy*7 + ix : 49;             // row 49 = zeros
                aoff[mi] = q*328 + kvb + half*8;
            }
            size_t tapbase = ((size_t)(c*25 + tap))*81920;   // 40*256*8
            const short *pbh[2], *pbl[2];
            #pragma unroll
            for (int ni = 0; ni < 2; ni++){
                int co = nq*64 + ni*32 + l31;
                size_t off = tapbase + ((size_t)((kv*20 + half)*256 + co))*8;
                pbh[ni] = w1h + off; pbl[ni] = w1l + off;
            }
            #pragma unroll 2
            for (int ks = 0; ks < 10; ks++){
                bf16x8 Ah[2], Al[2], Bh[2], Bl[2];
                #pragma unroll
                for (int mi = 0; mi < 2; mi++){
                    Ah[mi] = *(const bf16x8*)&xh[aoff[mi] + ks*16];
                    Al[mi] = *(const bf16x8*)&xl[aoff[mi] + ks*16];
                }
                #pragma unroll
                for (int ni = 0; ni < 2; ni++){
                    Bh[ni] = *(const bf16x8*)&pbh[ni][ks*4096];
                    Bl[ni] = *(const bf16x8*)&pbl[ni][ks*4096];
                }
                __builtin_amdgcn_s_setprio(1);
                #pragma unroll
                for (int mi = 0; mi < 2; mi++)
                    #pragma unroll
                    for (int ni = 0; ni < 2; ni++){
                        acc[mi][ni] = __builtin_amdgcn_mfma_f32_32x32x16_bf16(Ah[mi], Bh[ni], acc[mi][ni], 0, 0, 0);
                        acc[mi][ni] = __builtin_amdgcn_mfma_f32_32x32x16_bf16(Ah[mi], Bl[ni], acc[mi][ni], 0, 0, 0);
                        acc[mi][ni] = __builtin_amdgcn_mfma_f32_32x32x16_bf16(Al[mi], Bh[ni], acc[mi][ni], 0, 0, 0);
                    }
                __builtin_amdgcn_s_setprio(0);
            }
        }
        __syncthreads();   // all conv1 LDS reads complete -> region becomes f32 scratch
        // 2-way K-combine through LDS: kv=1 writes partials, kv=0 adds.
        float* scr = (float*)smem;
        const int g = s*4 + nq;                          // 8 groups x 16 KB
        if (kv){
            #pragma unroll
            for (int t4 = 0; t4 < 4; t4++){
                const int mi = t4 >> 1, ni = t4 & 1;
                #pragma unroll
                for (int rq = 0; rq < 4; rq++){
                    f32x4 v;
                    v[0] = acc[mi][ni][rq*4+0]; v[1] = acc[mi][ni][rq*4+1];
                    v[2] = acc[mi][ni][rq*4+2]; v[3] = acc[mi][ni][rq*4+3];
                    *(f32x4*)&scr[g*4096 + (t4*4 + rq)*256 + lane*4] = v;
                }
            }
        }
        __syncthreads();
        if (!kv){
            #pragma unroll
            for (int t4 = 0; t4 < 4; t4++){
                const int mi = t4 >> 1, ni = t4 & 1;
                #pragma unroll
                for (int rq = 0; rq < 4; rq++){
                    f32x4 v = *(const f32x4*)&scr[g*4096 + (t4*4 + rq)*256 + lane*4];
                    acc[mi][ni][rq*4+0] += v[0]; acc[mi][ni][rq*4+1] += v[1];
                    acc[mi][ni][rq*4+2] += v[2]; acc[mi][ni][rq*4+3] += v[3];
                }
            }
        }
        __syncthreads();   // scratch reads complete -> region becomes conv2 input
        if (!kv){
            // epilogue: BN + LReLU -> conv2-in (hi/lo)
            const int co = nq*64;
            float sc[2], mm[2], bb[2];
            #pragma unroll
            for (int ni = 0; ni < 2; ni++){
                int cc = co + ni*32 + l31;
                sc[ni] = G1[c*256 + cc] * rsqrtf(V1[c*256 + cc] + BNEPS);
                mm[ni] = M1[c*256 + cc];
                bb[ni] = B1[c*256 + cc];
            }
            short* yh = smem + (s*2 + 0)*13200;
            short* yl = smem + (s*2 + 1)*13200;
            yh[49*264 + nq*64 + (lane & 31)] = 0;  yh[49*264 + nq*64 + 32 + (lane & 31)] = 0;
            yl[49*264 + nq*64 + (lane & 31)] = 0;  yl[49*264 + nq*64 + 32 + (lane & 31)] = 0;
            #pragma unroll
            for (int mi = 0; mi < 2; mi++)
                #pragma unroll
                for (int ni = 0; ni < 2; ni++)
                    #pragma unroll
                    for (int r = 0; r < 16; r++){
                        int p = mi*32 + (r & 3) + 8*(r >> 2) + 4*half;
                        if (p < 49){
                            float y = (acc[mi][ni][r] - mm[ni])*sc[ni] + bb[ni];
                            y = (y >= 0.f) ? y : ALPHA*y;
                            short h = f2bf(y), l = f2bf(y - bf2f(h));
                            int o = p*264 + co + ni*32 + l31;
                            yh[o] = h; yl[o] = l;
                        }
                    }
        }
    }
    __syncthreads();

    // ================= conv2: 7x7x256 -> 14x14x128 (s=2, pads 3,2), parity split =================
    {
        const int s = wid & 1, par = (wid >> 1) & 3, nh = wid >> 3;
        const int pi = par >> 1, pj = par & 1;
        const int c = binfo[2 + s];
        const short* xh = smem + (s*2 + 0)*13200;
        const short* xl = smem + (s*2 + 1)*13200;
        f32x16 acc[2][2];
        #pragma unroll
        for (int mi = 0; mi < 2; mi++)
            #pragma unroll
            for (int ni = 0; ni < 2; ni++)
                #pragma unroll
                for (int r = 0; r < 16; r++) acc[mi][ni][r] = 0.f;
        int py[2], px[2], pok[2];
        #pragma unroll
        for (int mi = 0; mi < 2; mi++){
            int p = mi*32 + l31;
            py[mi] = p/7; px[mi] = p%7; pok[mi] = (p < 49);
        }
        const int nky = pi ? 3 : 2, kyb = pi ? 0 : 1;
        const int nkx = pj ? 3 : 2, kxb = pj ? 0 : 1;
        #pragma unroll 1
        for (int ty = 0; ty < nky; ty++){
            int ky = kyb + 2*ty;
            int dy = (pi + ky - 3) / 2;
            #pragma unroll 1
            for (int tx = 0; tx < nkx; tx++){
                int kx = kxb + 2*tx;
                int dx = (pj + kx - 3) / 2;
                int tap = ky*5 + kx;
                int aoff[2];
                #pragma unroll
                for (int mi = 0; mi < 2; mi++){
                    int u = py[mi] + dy, v = px[mi] + dx;
                    bool ok = pok[mi] & (u >= 0) & (u < 7) & (v >= 0) & (v < 7);
                    int q = ok ? u*7 + v : 49;
                    aoff[mi] = q*264 + half*8;
                }
                size_t tapbase = ((size_t)(c*25 + tap))*32768;   // 32*128*8
                const short *pbh[2], *pbl[2];
                #pragma unroll
                for (int ni = 0; ni < 2; ni++){
                    int co = nh*64 + ni*32 + l31;
                    size_t off = tapbase + ((size_t)(half*128 + co))*8;
                    pbh[ni] = w2h + off; pbl[ni] = w2l + off;
                }
                #pragma unroll 2
                for (int ks = 0; ks < 16; ks++){
                    bf16x8 Ah[2], Al[2], Bh[2], Bl[2];
                    #pragma unroll
                    for (int mi = 0; mi < 2; mi++){
                        Ah[mi] = *(const bf16x8*)&xh[aoff[mi] + ks*16];
                        Al[mi] = *(const bf16x8*)&xl[aoff[mi] + ks*16];
                    }
                    #pragma unroll
                    for (int ni = 0; ni < 2; ni++){
                        Bh[ni] = *(const bf16x8*)&pbh[ni][ks*2048];
                        Bl[ni] = *(const bf16x8*)&pbl[ni][ks*2048];
                    }
                    __builtin_amdgcn_s_setprio(1);
                    #pragma unroll
                    for (int mi = 0; mi < 2; mi++)
                        #pragma unroll
                        for (int ni = 0; ni < 2; ni++){
                            acc[mi][ni] = __builtin_amdgcn_mfma_f32_32x32x16_bf16(Ah[mi], Bh[ni], acc[mi][ni], 0, 0, 0);
                            acc[mi][ni] = __builtin_amdgcn_mfma_f32_32x32x16_bf16(Ah[mi], Bl[ni], acc[mi][ni], 0, 0, 0);
                            acc[mi][ni] = __builtin_amdgcn_mfma_f32_32x32x16_bf16(Al[mi], Bh[ni], acc[mi][ni], 0, 0, 0);
                        }
                    __builtin_amdgcn_s_setprio(0);
                }
            }
        }
        __syncthreads();   // all conv2 LDS reads complete; smem free
        float sc[2], mm[2], bb[2];
        #pragma unroll
        for (int ni = 0; ni < 2; ni++){
            int co = nh*64 + ni*32 + l31;
            sc[ni] = G2[c*128 + co] * rsqrtf(V2[c*128 + co] + BNEPS);
            mm[ni] = M2[c*128 + co];
            bb[ni] = B2[c*128 + co];
        }
        float* h2f = (float*)smem;          // 196*132
        float* wk3 = (float*)smem + 25872;  // 3200
        #pragma unroll 1
        for (int sp = 0; sp < 2; sp++){
            if (s == sp){
                #pragma unroll
                for (int mi = 0; mi < 2; mi++)
                    #pragma unroll
                    for (int ni = 0; ni < 2; ni++)
                        #pragma unroll
                        for (int r = 0; r < 16; r++){
                            int p = mi*32 + (r & 3) + 8*(r >> 2) + 4*half;
                            if (p < 49){
                                int oy = p / 7, ox = p % 7;
                                int q2 = (2*oy + pi)*14 + (2*ox + pj);
                                float y = (acc[mi][ni][r] - mm[ni])*sc[ni] + bb[ni];
                                y = (y >= 0.f) ? y : ALPHA*y;
                                h2f[q2*132 + nh*64 + ni*32 + l31] = y;
                            }
                        }
            }
            int cs = binfo[2 + sp];
            for (int i = tid; i < 3200; i += 1024) wk3[i] = K3[cs*3200 + i];
            __syncthreads();
            // conv3: 14x14x128 -> 28x28x1, s=2, pads (3,2), tanh
            int p3 = tid;
            if (p3 < 784){
                int oi = p3 / 28, oj = p3 % 28;
                float a3 = 0.f;
                #pragma unroll
                for (int ky = 0; ky < 5; ky++){
                    int t = oi + ky - 3;
                    if (t < 0 || (t & 1) || t >= 28) continue;
                    int u = t >> 1;
                    #pragma unroll
                    for (int kx = 0; kx < 5; kx++){
                        int ss2 = oj + kx - 3;
                        if (ss2 < 0 || (ss2 & 1) || ss2 >= 28) continue;
                        int v = ss2 >> 1;
                        const float* xr = &h2f[(u*14 + v)*132];
                        const float* w = &wk3[(ky*5 + kx)*128];
                        #pragma unroll
                        for (int cc = 0; cc < 32; cc++){
                            float4 xv = *(const float4*)&xr[4*cc];
                            float4 wv = *(const float4*)&w[4*cc];
                            a3 += xv.x*wv.x + xv.y*wv.y + xv.z*wv.z + xv.w*wv.w;
                        }
                    }
                }
                out[binfo[sp]*784 + p3] = tanhf(a3);
            }
            __syncthreads();   // before next sp overwrites h2f
        }
    }
}

// =======================================================================================
// Fallback path (verified R5 kernel) — used when ws_size is too small for the MFMA path.
// =======================================================================================
#define NOISE 100
#define EMB   50
#define CIN1  306
#define S1    52

template<int PH>
__device__ __forceinline__ void conv1_full(const float* __restrict__ xt1, float* __restrict__ xt2,
                                           const float* __restrict__ wbase,
                                           float sc, float mm, float bb, int co){
    constexpr int OY0 = PH ? 4 : 0;
    constexpr int NOY = PH ? 3 : 4;
    float acc[NOY*7];
    #pragma unroll
    for (int i = 0; i < NOY*7; i++) acc[i] = 0.f;
    #pragma unroll 1
    for (int ci = 0; ci < CIN1; ci++){
        float xr[49];
        #pragma unroll
        for (int r = 0; r < 12; r++) *(float4*)&xr[4*r] = *(const float4*)&xt1[ci*S1 + 4*r];
        xr[48] = xt1[ci*S1 + 48];
        const float* wci = wbase + ci*256;
        #pragma unroll
        for (int ky = 0; ky < 5; ky++)
            #pragma unroll
            for (int kx = 0; kx < 5; kx++){
                float w = wci[(ky*5 + kx)*CIN1*256];
                #pragma unroll
                for (int oy = OY0; oy < OY0 + NOY; oy++){
                    int iy = oy + ky - 2;
                    if (iy < 0 || iy >= 7) continue;
                    #pragma unroll
                    for (int ox = 0; ox < 7; ox++){
                        int ix = ox + kx - 2;
                        if (ix < 0 || ix >= 7) continue;
                        acc[(oy - OY0)*7 + ox] += xr[iy*7 + ix] * w;
                    }
                }
            }
    }
    #pragma unroll
    for (int i = 0; i < NOY*7; i++){
        float y = (acc[i] - mm)*sc + bb;
        xt2[co*S1 + OY0*7 + i] = (y >= 0.f) ? y : ALPHA*y;
    }
}

template<int Q>
__device__ __forceinline__ void conv2_full(const float* __restrict__ xt2, float* __restrict__ xt3,
                                           const float* __restrict__ wbase,
                                           float sc, float mm, float bb, int co){
    float acc[49];
    #pragma unroll
    for (int i = 0; i < 49; i++) acc[i] = 0.f;
    #pragma unroll 1
    for (int ci = 0; ci < 256; ci++){
        float xr[49];
        #pragma unroll
        for (int r = 0; r < 12; r++) *(float4*)&xr[4*r] = *(const float4*)&xt2[ci*S1 + 4*r];
        xr[48] = xt2[ci*S1 + 48];
        const float* wci = wbase + ci*128;
        #pragma unroll
        for (int ky = 0; ky < 5; ky++)
            #pragma unroll
            for (int kx = 0; kx < 5; kx++){
                float w = wci[(ky*5 + kx)*256*128];
                #pragma unroll
                for (int ii = 0; ii < 49; ii++){
                    int p2 = Q*49 + ii;
                    int i = p2 / 14, j = p2 % 14;
                    int t = i + ky - 3, s = j + kx - 3;
                    if (t < 0 || (t & 1) || t >= 14) continue;
                    if (s < 0 || (s & 1) || s >= 14) continue;
                    acc[ii] += xr[(t >> 1)*7 + (s >> 1)] * w;
                }
            }
    }
    #pragma unroll
    for (int ii = 0; ii < 49; ii++){
        int p2 = Q*49 + ii;
        float y = (acc[ii] - mm)*sc + bb;
        xt3[p2*132 + co] = (y >= 0.f) ? y : ALPHA*y;
    }
}

__global__ __launch_bounds__(512, 2)
void fused_k(const float* __restrict__ noise, const int* __restrict__ labels,
             const float* __restrict__ emb,   const float* __restrict__ Wd,
             const float* __restrict__ g1,    const float* __restrict__ b1,
             const float* __restrict__ m1,    const float* __restrict__ v1,
             const float* __restrict__ K1,
             const float* __restrict__ G1, const float* __restrict__ B1,
             const float* __restrict__ M1, const float* __restrict__ V1,
             const float* __restrict__ K2,
             const float* __restrict__ G2, const float* __restrict__ B2,
             const float* __restrict__ M2, const float* __restrict__ V2,
             const float* __restrict__ K3,
             const int* __restrict__ order,
             float* __restrict__ out){
    __shared__ __align__(16) unsigned char smem[53248 + 103488];
    __shared__ float xin[152];
    float* xt2 = (float*)smem;
    float* wk  = (float*)smem;
    float* xt1 = (float*)(smem + 53248);
    float* xt3 = (float*)(smem + 53248);

    const int tid = threadIdx.x;
    const int idx = ((blockIdx.x & 7) << 6) | (blockIdx.x >> 3);
    const int b = order[idx];
    const int c = labels[b];

    if (tid < 150)
        xin[tid] = (tid < NOISE) ? noise[b*NOISE + tid] : emb[c*EMB + (tid - NOISE)];
    __syncthreads();
    {
        const int co = tid & 255;
        const int p0 = (tid >> 8) * 24;
        float acc[25];
        #pragma unroll
        for (int i = 0; i < 25; i++) acc[i] = 0.f;
        #pragma unroll 1
        for (int k = 0; k < 150; k++){
            float x = xin[k];
            const float* wr = Wd + k*12544 + p0*256 + co;
            #pragma unroll
            for (int i = 0; i < 25; i++) acc[i] += x * wr[i*256];
        }
        #pragma unroll
        for (int i = 0; i < 25; i++){
            int j = (p0 + i)*256 + co;
            float sc = g1[j] * rsqrtf(v1[j] + BNEPS);
            float y = (acc[i] - m1[j])*sc + b1[j];
            y = (y >= 0.f) ? y : ALPHA*y;
            xt1[co*S1 + p0 + i] = y;
        }
        if (tid < EMB){
            float v = xin[NOISE + tid];
            #pragma unroll
            for (int p = 0; p < 49; p++) xt1[(256 + tid)*S1 + p] = v;
        }
    }
    __syncthreads();
    {
        const int co = tid & 255;
        const int ph = tid >> 8;
        const float* wbase = K1 + (size_t)c*25*CIN1*256 + co;
        float sc = G1[c*256 + co] * rsqrtf(V1[c*256 + co] + BNEPS);
        float mm = M1[c*256 + co], bb = B1[c*256 + co];
        if (ph == 0) conv1_full<0>(xt1, xt2, wbase, sc, mm, bb, co);
        else         conv1_full<1>(xt1, xt2, wbase, sc, mm, bb, co);
    }
    __syncthreads();
    {
        const int co = tid & 127;
        const int q  = tid >> 7;
        const float* wbase = K2 + (size_t)c*25*256*128 + co;
        float sc = G2[c*128 + co] * rsqrtf(V2[c*128 + co] + BNEPS);
        float mm = M2[c*128 + co], bb = B2[c*128 + co];
        switch (q){
            case 0: conv2_full<0>(xt2, xt3, wbase, sc, mm, bb, co); break;
            case 1: conv2_full<1>(xt2, xt3, wbase, sc, mm, bb, co); break;
            case 2: conv2_full<2>(xt2, xt3, wbase, sc, mm, bb, co); break;
            default:conv2_full<3>(xt2, xt3, wbase, sc, mm, bb, co); break;
        }
    }
    __syncthreads();
    for (int i = tid; i < 3200; i += 512) wk[i] = K3[c*3200 + i];
    __syncthreads();
    #pragma unroll 1
    for (int rep = 0; rep < 2; rep++){
        int p3 = tid + rep*512;
        if (p3 < 784){
            int i = p3 / 28, j = p3 - (p3/28)*28;
            float acc = 0.f;
            #pragma unroll
            for (int ky = 0; ky < 5; ky++){
                int t = i + ky - 3;
                if (t < 0 || (t & 1) || t >= 28) continue;
                int u = t >> 1;
                #pragma unroll
                for (int kx = 0; kx < 5; kx++){
                    int s = j + kx - 3;
                    if (s < 0 || (s & 1) || s >= 28) continue;
                    int v = s >> 1;
                    const float* xr = &xt3[(u*14 + v)*132];
                    const float* w = &wk[(ky*5 + kx)*128];
                    #pragma unroll
                    for (int cc = 0; cc < 32; cc++){
                        float4 xv = *(const float4*)&xr[4*cc];
                        float4 wv = *(const float4*)&w[4*cc];
                        acc += xv.x*wv.x + xv.y*wv.y + xv.z*wv.z + xv.w*wv.w;
                    }
                }
            }
            out[b*784 + p3] = tanhf(acc);
        }
    }
}

extern "C" void kernel_launch(void* const* d_in, const int* in_sizes, int n_in,
                              void* d_out, int out_size, void* d_ws, size_t ws_size,
                              hipStream_t stream){
    const float* noise = (const float*)d_in[0];
    const int*   labels= (const int*)  d_in[1];
    const float* emb   = (const float*)d_in[2];
    const float* Wd    = (const float*)d_in[3];
    const float* g1    = (const float*)d_in[4];
    const float* b1    = (const float*)d_in[5];
    const float* m1    = (const float*)d_in[6];
    const float* v1    = (const float*)d_in[7];
    const float* K1    = (const float*)d_in[8];
    const float* G1    = (const float*)d_in[9];
    const float* B1    = (const float*)d_in[10];
    const float* M1    = (const float*)d_in[11];
    const float* V1    = (const float*)d_in[12];
    const float* K2    = (const float*)d_in[13];
    const float* G2    = (const float*)d_in[14];
    const float* B2    = (const float*)d_in[15];
    const float* M2    = (const float*)d_in[16];
    const float* V2    = (const float*)d_in[17];
    const float* K3    = (const float*)d_in[18];
    float* outp = (float*)d_out;

    const size_t NEED = 4096 + 2*(size_t)N1*2 + 2*(size_t)N2*2 + 2*(size_t)512*49*320*2;
    int* order = (int*)d_ws;

    if (ws_size >= NEED){
        short* w1h = (short*)((char*)d_ws + 4096);
        short* w1l = w1h + N1;
        short* w2h = w1l + N1;
        short* w2l = w2h + N2;
        short* xgH = w2l + N2;
        short* xgL = xgH + (size_t)512*49*320;
        aux_k <<<1 + DENSE_BLKS + PREP_BLKS, 256, 0, stream>>>(
            noise, labels, emb, Wd, g1, b1, m1, v1, K1, K2,
            w1h, w1l, w2h, w2l, xgH, xgL, order);
        main_k <<<256, 1024, 0, stream>>>(labels, order, xgH, xgL, w1h, w1l, w2h, w2l,
                                          G1, B1, M1, V1, G2, B2, M2, V2, K3, outp);
    } else {
        // fallback: verified R5 path (needs only 2 KB ws)
        sort_k <<<1, 512, 0, stream>>>(labels, order);
        fused_k<<<512, 512, 0, stream>>>(noise, labels, emb, Wd, g1, b1, m1, v1,
                                         K1, G1, B1, M1, V1,
                                         K2, G2, B2, M2, V2, K3, order, outp);
    }
}

// Round 7
// 674.433 us; speedup vs baseline: 3.5206x; 1.1103x over previous
//
#include <hip/hip_runtime.h>

#define ALPHA 0.3f
#define BNEPS 1e-3f

typedef __attribute__((ext_vector_type(8))) short bf16x8;
typedef __attribute__((ext_vector_type(4))) float f32x4;

__device__ __forceinline__ short f2bf(float x){
    unsigned u = __float_as_uint(x);
    unsigned r = (u + 0x7FFFu + ((u >> 16) & 1u)) >> 16;   // RNE
    return (short)r;
}
__device__ __forceinline__ float bf2f(short s){
    return __uint_as_float(((unsigned)(unsigned short)s) << 16);
}

#define N1 20480000   // 250*40*256*8
#define N2 8192000    // 250*32*128*8
#define T1 2560000    // 250*40*256
#define PREP_BLKS 14000   // (T1 + N2/8)/256
#define DENSE_BLKS 1568   // 49*32

// ---------------- routing: counting sort of samples by class (512-thread, fallback) ----
__global__ void sort_k(const int* __restrict__ labels, int* __restrict__ order){
    __shared__ int cnt[10], offs[10];
    int tid = threadIdx.x;
    if (tid < 10) cnt[tid] = 0;
    __syncthreads();
    int lab = labels[tid];
    atomicAdd(&cnt[lab], 1);
    __syncthreads();
    if (tid == 0){
        int s = 0;
        for (int c = 0; c < 10; c++){ offs[c] = s; s += cnt[c]; }
    }
    __syncthreads();
    int pos = atomicAdd(&offs[lab], 1);
    order[pos] = tid;
}

// ---------------- fused aux kernel: sort (blk 0) + dense (blks 1..1568) + prep (rest) ----
// prep: fp32 -> bf16 hi/lo, B-fragment layout.
//   W1T: [ct (250)][chunk=ci/8 (40)][co (256)][ci%8]   ci in [0,320), >=306 zero
//   W2T: [ct][chunk=ci/8 (32)][co (128)][ci%8]
// dense: 150->12544 + BN1 + LReLU -> xg hi bf16 (lo not needed: conv1 is 2-term).
__global__ __launch_bounds__(256)
void aux_k(const float* __restrict__ noise, const int* __restrict__ labels,
           const float* __restrict__ emb,   const float* __restrict__ Wd,
           const float* __restrict__ g1, const float* __restrict__ b1,
           const float* __restrict__ m1, const float* __restrict__ v1,
           const float* __restrict__ K1, const float* __restrict__ K2,
           short* __restrict__ w1h, short* __restrict__ w1l,
           short* __restrict__ w2h, short* __restrict__ w2l,
           short* __restrict__ xgH, short* __restrict__ xgL,
           int* __restrict__ order){
    const int bid = blockIdx.x;
    const int tid = threadIdx.x;

    if (bid == 0){
        // ---- counting sort of 512 labels with 256 threads ----
        __shared__ int cnt[10], offs[10];
        if (tid < 10) cnt[tid] = 0;
        __syncthreads();
        int l0 = labels[tid], l1 = labels[tid + 256];
        atomicAdd(&cnt[l0], 1);
        atomicAdd(&cnt[l1], 1);
        __syncthreads();
        if (tid == 0){
            int s = 0;
            for (int c = 0; c < 10; c++){ offs[c] = s; s += cnt[c]; }
        }
        __syncthreads();
        int p0 = atomicAdd(&offs[l0], 1);
        order[p0] = tid;
        int p1 = atomicAdd(&offs[l1], 1);
        order[p1] = tid + 256;
        return;
    }

    if (bid <= DENSE_BLKS){
        // ---- dense: one (q, 16-sample tile) per block ----
        __shared__ float xs[16][152];
        const int b2 = bid - 1;
        const int q  = b2 % 49;
        const int st = b2 / 49;
        for (int i = tid; i < 16*150; i += 256){
            int ss = i / 150, k = i % 150;
            int b = st*16 + ss;
            xs[ss][k] = (k < 100) ? noise[b*100 + k] : emb[labels[b]*50 + (k-100)];
        }
        __syncthreads();
        const int co = tid;
        const int j = q*256 + co;
        float acc[16];
        #pragma unroll
        for (int ss = 0; ss < 16; ss++) acc[ss] = 0.f;
        #pragma unroll 2
        for (int k = 0; k < 150; k++){
            float w = Wd[k*12544 + j];
            #pragma unroll
            for (int ss = 0; ss < 16; ss++)
                acc[ss] += xs[ss][k] * w;
        }
        float sc = g1[j] * rsqrtf(v1[j] + BNEPS);
        float mm = m1[j], bb = b1[j];
        #pragma unroll
        for (int ss = 0; ss < 16; ss++){
            float y = (acc[ss] - mm)*sc + bb;
            y = (y >= 0.f) ? y : ALPHA*y;
            size_t o = ((size_t)(st*16 + ss)*49 + q)*320 + co;
            xgH[o] = f2bf(y);
        }
        {
            int ss = tid >> 4, cg = tid & 15;
            #pragma unroll
            for (int cj = 0; cj < 4; cj++){
                int col = 256 + cg*4 + cj;
                float v = (col < 306) ? xs[ss][100 + col - 256] : 0.f;
                size_t o = ((size_t)(st*16 + ss)*49 + q)*320 + col;
                xgH[o] = f2bf(v);
            }
        }
        return;
    }

    // ---- prep ----
    int t = (bid - 1 - DENSE_BLKS) * 256 + tid;
    if (t < T1){
        int co = t & 255;
        int ch = (t >> 8) % 40;
        int ct = (t >> 8) / 40;
        bf16x8 h, l;
        #pragma unroll
        for (int j = 0; j < 8; j++){
            int ci = ch*8 + j;
            float w = (ci < 306) ? K1[((size_t)ct*306 + ci)*256 + co] : 0.f;
            short hh = f2bf(w);
            h[j] = hh;
            l[j] = f2bf(w - bf2f(hh));
        }
        size_t dst = (size_t)t * 8;
        *(bf16x8*)&w1h[dst] = h;
        *(bf16x8*)&w1l[dst] = l;
    } else {
        int tt = t - T1;
        int co = tt & 127;
        int ch = (tt >> 7) & 31;
        int ct = tt >> 12;
        bf16x8 h, l;
        #pragma unroll
        for (int j = 0; j < 8; j++){
            int ci = ch*8 + j;
            float w = K2[((size_t)ct*256 + ci)*128 + co];
            short hh = f2bf(w);
            h[j] = hh;
            l[j] = f2bf(w - bf2f(hh));
        }
        size_t dst = (size_t)tt * 8;
        *(bf16x8*)&w2h[dst] = h;
        *(bf16x8*)&w2l[dst] = l;
    }
}

// ---------------- main: conv1 (2-term MFMA) + conv2 (3-term) + conv3 (VALU), 2 samples/block ----
// conv1 2-term: x ~ xh only (A-residual dropped; rel err ~2^-9), W = wh + wl exact to 2^-16.
// 1024 threads = 16 waves -> 4 waves/SIMD at 1 block/CU.
__global__ __launch_bounds__(1024, 1)
void main_k(const int* __restrict__ labels, const int* __restrict__ order,
            const short* __restrict__ xgH, const short* __restrict__ xgL,
            const short* __restrict__ w1h, const short* __restrict__ w1l,
            const short* __restrict__ w2h, const short* __restrict__ w2l,
            const float* __restrict__ G1, const float* __restrict__ B1,
            const float* __restrict__ M1, const float* __restrict__ V1,
            const float* __restrict__ G2, const float* __restrict__ B2,
            const float* __restrict__ M2, const float* __restrict__ V2,
            const float* __restrict__ K3, float* __restrict__ out){
    __shared__ __align__(16) short smem[65600];          // 131,200 B
    __shared__ int binfo[4];
    const int tid = threadIdx.x;
    const int idx = ((blockIdx.x & 7) << 5) | (blockIdx.x >> 3);   // XCD swizzle, 256 blocks
    if (tid < 2){
        int b = order[2*idx + tid];
        binfo[tid] = b;
        binfo[2 + tid] = labels[b];
    }
    {   // zero LDS (padding rows rely on this)
        uint4 z; z.x = z.y = z.z = z.w = 0;
        uint4* p = (uint4*)smem;
        for (int i = tid; i < 8200; i += 1024) p[i] = z;
    }
    __syncthreads();
    // copy xcat rows (s,q): 98 rows x 40 uint4 (hi plane only; conv1 is 2-term)
    for (int i = tid; i < 3920; i += 1024){
        int t = i % 40, w = i / 40;
        int q = w % 49, s = w / 49;
        const short* src = xgH + ((size_t)binfo[s]*49 + q)*320;
        *(uint4*)&smem[(s*2)*16400 + q*328 + t*8] = *(const uint4*)&src[t*8];
    }
    __syncthreads();

    const int lane = tid & 63, wid = tid >> 6;
    const int l31 = lane & 31, half = lane >> 5;
    typedef __attribute__((ext_vector_type(16))) float f32x16;

    // ================= conv1: 7x7x306 -> 7x7x256 (s=1, pads 2,2), 32x32x16 MFMA, 2-term ==========
    {
        const int s = wid & 1, kv = (wid >> 1) & 1, nq = wid >> 2;   // nq 0..3
        const int c = binfo[2 + s];
        const short* xh = smem + (s*2 + 0)*16400;
        const int kvb = kv*160;
        f32x16 acc[2][2];
        #pragma unroll
        for (int mi = 0; mi < 2; mi++)
            #pragma unroll
            for (int ni = 0; ni < 2; ni++)
                #pragma unroll
                for (int r = 0; r < 16; r++) acc[mi][ni][r] = 0.f;
        int py[2], px[2], pok[2];
        #pragma unroll
        for (int mi = 0; mi < 2; mi++){
            int p = mi*32 + l31;
            py[mi] = p/7; px[mi] = p%7; pok[mi] = (p < 49);
        }
        #pragma unroll 1
        for (int tap = 0; tap < 25; tap++){
            int ky = tap/5, kx = tap%5;
            int aoff[2];
            #pragma unroll
            for (int mi = 0; mi < 2; mi++){
                int iy = py[mi] + ky - 2, ix = px[mi] + kx - 2;
                bool ok = pok[mi] & (iy >= 0) & (iy < 7) & (ix >= 0) & (ix < 7);
                int q = ok ? iy*7 + ix : 49;             // row 49 = zeros
                aoff[mi] = q*328 + kvb + half*8;
            }
            size_t tapbase = ((size_t)(c*25 + tap))*81920;   // 40*256*8
            const short *pbh[2], *pbl[2];
            #pragma unroll
            for (int ni = 0; ni < 2; ni++){
                int co = nq*64 + ni*32 + l31;
                size_t off = tapbase + ((size_t)((kv*20 + half)*256 + co))*8;
                pbh[ni] = w1h + off; pbl[ni] = w1l + off;
            }
            #pragma unroll 2
            for (int ks = 0; ks < 10; ks++){
                bf16x8 Ah[2], Bh[2], Bl[2];
                #pragma unroll
                for (int mi = 0; mi < 2; mi++)
                    Ah[mi] = *(const bf16x8*)&xh[aoff[mi] + ks*16];
                #pragma unroll
                for (int ni = 0; ni < 2; ni++){
                    Bh[ni] = *(const bf16x8*)&pbh[ni][ks*4096];
                    Bl[ni] = *(const bf16x8*)&pbl[ni][ks*4096];
                }
                __builtin_amdgcn_s_setprio(1);
                #pragma unroll
                for (int mi = 0; mi < 2; mi++)
                    #pragma unroll
                    for (int ni = 0; ni < 2; ni++){
                        acc[mi][ni] = __builtin_amdgcn_mfma_f32_32x32x16_bf16(Ah[mi], Bh[ni], acc[mi][ni], 0, 0, 0);
                        acc[mi][ni] = __builtin_amdgcn_mfma_f32_32x32x16_bf16(Ah[mi], Bl[ni], acc[mi][ni], 0, 0, 0);
                    }
                __builtin_amdgcn_s_setprio(0);
            }
        }
        __syncthreads();   // all conv1 LDS reads complete -> region becomes f32 scratch
        // 2-way K-combine through LDS: kv=1 writes partials, kv=0 adds.
        float* scr = (float*)smem;
        const int g = s*4 + nq;                          // 8 groups x 16 KB
        if (kv){
            #pragma unroll
            for (int t4 = 0; t4 < 4; t4++){
                const int mi = t4 >> 1, ni = t4 & 1;
                #pragma unroll
                for (int rq = 0; rq < 4; rq++){
                    f32x4 v;
                    v[0] = acc[mi][ni][rq*4+0]; v[1] = acc[mi][ni][rq*4+1];
                    v[2] = acc[mi][ni][rq*4+2]; v[3] = acc[mi][ni][rq*4+3];
                    *(f32x4*)&scr[g*4096 + (t4*4 + rq)*256 + lane*4] = v;
                }
            }
        }
        __syncthreads();
        if (!kv){
            #pragma unroll
            for (int t4 = 0; t4 < 4; t4++){
                const int mi = t4 >> 1, ni = t4 & 1;
                #pragma unroll
                for (int rq = 0; rq < 4; rq++){
                    f32x4 v = *(const f32x4*)&scr[g*4096 + (t4*4 + rq)*256 + lane*4];
                    acc[mi][ni][rq*4+0] += v[0]; acc[mi][ni][rq*4+1] += v[1];
                    acc[mi][ni][rq*4+2] += v[2]; acc[mi][ni][rq*4+3] += v[3];
                }
            }
        }
        __syncthreads();   // scratch reads complete -> region becomes conv2 input
        if (!kv){
            // epilogue: BN + LReLU -> conv2-in (hi/lo)
            const int co = nq*64;
            float sc[2], mm[2], bb[2];
            #pragma unroll
            for (int ni = 0; ni < 2; ni++){
                int cc = co + ni*32 + l31;
                sc[ni] = G1[c*256 + cc] * rsqrtf(V1[c*256 + cc] + BNEPS);
                mm[ni] = M1[c*256 + cc];
                bb[ni] = B1[c*256 + cc];
            }
            short* yh = smem + (s*2 + 0)*13200;
            short* yl = smem + (s*2 + 1)*13200;
            yh[49*264 + nq*64 + (lane & 31)] = 0;  yh[49*264 + nq*64 + 32 + (lane & 31)] = 0;
            yl[49*264 + nq*64 + (lane & 31)] = 0;  yl[49*264 + nq*64 + 32 + (lane & 31)] = 0;
            #pragma unroll
            for (int mi = 0; mi < 2; mi++)
                #pragma unroll
                for (int ni = 0; ni < 2; ni++)
                    #pragma unroll
                    for (int r = 0; r < 16; r++){
                        int p = mi*32 + (r & 3) + 8*(r >> 2) + 4*half;
                        if (p < 49){
                            float y = (acc[mi][ni][r] - mm[ni])*sc[ni] + bb[ni];
                            y = (y >= 0.f) ? y : ALPHA*y;
                            short h = f2bf(y), l = f2bf(y - bf2f(h));
                            int o = p*264 + co + ni*32 + l31;
                            yh[o] = h; yl[o] = l;
                        }
                    }
        }
    }
    __syncthreads();

    // ================= conv2: 7x7x256 -> 14x14x128 (s=2, pads 3,2), parity split, 3-term =========
    {
        const int s = wid & 1, par = (wid >> 1) & 3, nh = wid >> 3;
        const int pi = par >> 1, pj = par & 1;
        const int c = binfo[2 + s];
        const short* xh = smem + (s*2 + 0)*13200;
        const short* xl = smem + (s*2 + 1)*13200;
        f32x16 acc[2][2];
        #pragma unroll
        for (int mi = 0; mi < 2; mi++)
            #pragma unroll
            for (int ni = 0; ni < 2; ni++)
                #pragma unroll
                for (int r = 0; r < 16; r++) acc[mi][ni][r] = 0.f;
        int py[2], px[2], pok[2];
        #pragma unroll
        for (int mi = 0; mi < 2; mi++){
            int p = mi*32 + l31;
            py[mi] = p/7; px[mi] = p%7; pok[mi] = (p < 49);
        }
        const int nky = pi ? 3 : 2, kyb = pi ? 0 : 1;
        const int nkx = pj ? 3 : 2, kxb = pj ? 0 : 1;
        #pragma unroll 1
        for (int ty = 0; ty < nky; ty++){
            int ky = kyb + 2*ty;
            int dy = (pi + ky - 3) / 2;
            #pragma unroll 1
            for (int tx = 0; tx < nkx; tx++){
                int kx = kxb + 2*tx;
                int dx = (pj + kx - 3) / 2;
                int tap = ky*5 + kx;
                int aoff[2];
                #pragma unroll
                for (int mi = 0; mi < 2; mi++){
                    int u = py[mi] + dy, v = px[mi] + dx;
                    bool ok = pok[mi] & (u >= 0) & (u < 7) & (v >= 0) & (v < 7);
                    int q = ok ? u*7 + v : 49;
                    aoff[mi] = q*264 + half*8;
                }
                size_t tapbase = ((size_t)(c*25 + tap))*32768;   // 32*128*8
                const short *pbh[2], *pbl[2];
                #pragma unroll
                for (int ni = 0; ni < 2; ni++){
                    int co = nh*64 + ni*32 + l31;
                    size_t off = tapbase + ((size_t)(half*128 + co))*8;
                    pbh[ni] = w2h + off; pbl[ni] = w2l + off;
                }
                #pragma unroll 2
                for (int ks = 0; ks < 16; ks++){
                    bf16x8 Ah[2], Al[2], Bh[2], Bl[2];
                    #pragma unroll
                    for (int mi = 0; mi < 2; mi++){
                        Ah[mi] = *(const bf16x8*)&xh[aoff[mi] + ks*16];
                        Al[mi] = *(const bf16x8*)&xl[aoff[mi] + ks*16];
                    }
                    #pragma unroll
                    for (int ni = 0; ni < 2; ni++){
                        Bh[ni] = *(const bf16x8*)&pbh[ni][ks*2048];
                        Bl[ni] = *(const bf16x8*)&pbl[ni][ks*2048];
                    }
                    __builtin_amdgcn_s_setprio(1);
                    #pragma unroll
                    for (int mi = 0; mi < 2; mi++)
                        #pragma unroll
                        for (int ni = 0; ni < 2; ni++){
                            acc[mi][ni] = __builtin_amdgcn_mfma_f32_32x32x16_bf16(Ah[mi], Bh[ni], acc[mi][ni], 0, 0, 0);
                            acc[mi][ni] = __builtin_amdgcn_mfma_f32_32x32x16_bf16(Ah[mi], Bl[ni], acc[mi][ni], 0, 0, 0);
                            acc[mi][ni] = __builtin_amdgcn_mfma_f32_32x32x16_bf16(Al[mi], Bh[ni], acc[mi][ni], 0, 0, 0);
                        }
                    __builtin_amdgcn_s_setprio(0);
                }
            }
        }
        __syncthreads();   // all conv2 LDS reads complete; smem free
        float sc[2], mm[2], bb[2];
        #pragma unroll
        for (int ni = 0; ni < 2; ni++){
            int co = nh*64 + ni*32 + l31;
            sc[ni] = G2[c*128 + co] * rsqrtf(V2[c*128 + co] + BNEPS);
            mm[ni] = M2[c*128 + co];
            bb[ni] = B2[c*128 + co];
        }
        float* h2f = (float*)smem;          // 196*132
        float* wk3 = (float*)smem + 25872;  // 3200
        #pragma unroll 1
        for (int sp = 0; sp < 2; sp++){
            if (s == sp){
                #pragma unroll
                for (int mi = 0; mi < 2; mi++)
                    #pragma unroll
                    for (int ni = 0; ni < 2; ni++)
                        #pragma unroll
                        for (int r = 0; r < 16; r++){
                            int p = mi*32 + (r & 3) + 8*(r >> 2) + 4*half;
                            if (p < 49){
                                int oy = p / 7, ox = p % 7;
                                int q2 = (2*oy + pi)*14 + (2*ox + pj);
                                float y = (acc[mi][ni][r] - mm[ni])*sc[ni] + bb[ni];
                                y = (y >= 0.f) ? y : ALPHA*y;
                                h2f[q2*132 + nh*64 + ni*32 + l31] = y;
                            }
                        }
            }
            int cs = binfo[2 + sp];
            for (int i = tid; i < 3200; i += 1024) wk3[i] = K3[cs*3200 + i];
            __syncthreads();
            // conv3: 14x14x128 -> 28x28x1, s=2, pads (3,2), tanh
            int p3 = tid;
            if (p3 < 784){
                int oi = p3 / 28, oj = p3 % 28;
                float a3 = 0.f;
                #pragma unroll
                for (int ky = 0; ky < 5; ky++){
                    int t = oi + ky - 3;
                    if (t < 0 || (t & 1) || t >= 28) continue;
                    int u = t >> 1;
                    #pragma unroll
                    for (int kx = 0; kx < 5; kx++){
                        int ss2 = oj + kx - 3;
                        if (ss2 < 0 || (ss2 & 1) || ss2 >= 28) continue;
                        int v = ss2 >> 1;
                        const float* xr = &h2f[(u*14 + v)*132];
                        const float* w = &wk3[(ky*5 + kx)*128];
                        #pragma unroll
                        for (int cc = 0; cc < 32; cc++){
                            float4 xv = *(const float4*)&xr[4*cc];
                            float4 wv = *(const float4*)&w[4*cc];
                            a3 += xv.x*wv.x + xv.y*wv.y + xv.z*wv.z + xv.w*wv.w;
                        }
                    }
                }
                out[binfo[sp]*784 + p3] = tanhf(a3);
            }
            __syncthreads();   // before next sp overwrites h2f
        }
    }
}

// =======================================================================================
// Fallback path (verified R5 kernel) — used when ws_size is too small for the MFMA path.
// =======================================================================================
#define NOISE 100
#define EMB   50
#define CIN1  306
#define S1    52

template<int PH>
__device__ __forceinline__ void conv1_full(const float* __restrict__ xt1, float* __restrict__ xt2,
                                           const float* __restrict__ wbase,
                                           float sc, float mm, float bb, int co){
    constexpr int OY0 = PH ? 4 : 0;
    constexpr int NOY = PH ? 3 : 4;
    float acc[NOY*7];
    #pragma unroll
    for (int i = 0; i < NOY*7; i++) acc[i] = 0.f;
    #pragma unroll 1
    for (int ci = 0; ci < CIN1; ci++){
        float xr[49];
        #pragma unroll
        for (int r = 0; r < 12; r++) *(float4*)&xr[4*r] = *(const float4*)&xt1[ci*S1 + 4*r];
        xr[48] = xt1[ci*S1 + 48];
        const float* wci = wbase + ci*256;
        #pragma unroll
        for (int ky = 0; ky < 5; ky++)
            #pragma unroll
            for (int kx = 0; kx < 5; kx++){
                float w = wci[(ky*5 + kx)*CIN1*256];
                #pragma unroll
                for (int oy = OY0; oy < OY0 + NOY; oy++){
                    int iy = oy + ky - 2;
                    if (iy < 0 || iy >= 7) continue;
                    #pragma unroll
                    for (int ox = 0; ox < 7; ox++){
                        int ix = ox + kx - 2;
                        if (ix < 0 || ix >= 7) continue;
                        acc[(oy - OY0)*7 + ox] += xr[iy*7 + ix] * w;
                    }
                }
            }
    }
    #pragma unroll
    for (int i = 0; i < NOY*7; i++){
        float y = (acc[i] - mm)*sc + bb;
        xt2[co*S1 + OY0*7 + i] = (y >= 0.f) ? y : ALPHA*y;
    }
}

template<int Q>
__device__ __forceinline__ void conv2_full(const float* __restrict__ xt2, float* __restrict__ xt3,
                                           const float* __restrict__ wbase,
                                           float sc, float mm, float bb, int co){
    float acc[49];
    #pragma unroll
    for (int i = 0; i < 49; i++) acc[i] = 0.f;
    #pragma unroll 1
    for (int ci = 0; ci < 256; ci++){
        float xr[49];
        #pragma unroll
        for (int r = 0; r < 12; r++) *(float4*)&xr[4*r] = *(const float4*)&xt2[ci*S1 + 4*r];
        xr[48] = xt2[ci*S1 + 48];
        const float* wci = wbase + ci*128;
        #pragma unroll
        for (int ky = 0; ky < 5; ky++)
            #pragma unroll
            for (int kx = 0; kx < 5; kx++){
                float w = wci[(ky*5 + kx)*256*128];
                #pragma unroll
                for (int ii = 0; ii < 49; ii++){
                    int p2 = Q*49 + ii;
                    int i = p2 / 14, j = p2 % 14;
                    int t = i + ky - 3, s = j + kx - 3;
                    if (t < 0 || (t & 1) || t >= 14) continue;
                    if (s < 0 || (s & 1) || s >= 14) continue;
                    acc[ii] += xr[(t >> 1)*7 + (s >> 1)] * w;
                }
            }
    }
    #pragma unroll
    for (int ii = 0; ii < 49; ii++){
        int p2 = Q*49 + ii;
        float y = (acc[ii] - mm)*sc + bb;
        xt3[p2*132 + co] = (y >= 0.f) ? y : ALPHA*y;
    }
}

__global__ __launch_bounds__(512, 2)
void fused_k(const float* __restrict__ noise, const int* __restrict__ labels,
             const float* __restrict__ emb,   const float* __restrict__ Wd,
             const float* __restrict__ g1,    const float* __restrict__ b1,
             const float* __restrict__ m1,    const float* __restrict__ v1,
             const float* __restrict__ K1,
             const float* __restrict__ G1, const float* __restrict__ B1,
             const float* __restrict__ M1, const float* __restrict__ V1,
             const float* __restrict__ K2,
             const float* __restrict__ G2, const float* __restrict__ B2,
             const float* __restrict__ M2, const float* __restrict__ V2,
             const float* __restrict__ K3,
             const int* __restrict__ order,
             float* __restrict__ out){
    __shared__ __align__(16) unsigned char smem[53248 + 103488];
    __shared__ float xin[152];
    float* xt2 = (float*)smem;
    float* wk  = (float*)smem;
    float* xt1 = (float*)(smem + 53248);
    float* xt3 = (float*)(smem + 53248);

    const int tid = threadIdx.x;
    const int idx = ((blockIdx.x & 7) << 6) | (blockIdx.x >> 3);
    const int b = order[idx];
    const int c = labels[b];

    if (tid < 150)
        xin[tid] = (tid < NOISE) ? noise[b*NOISE + tid] : emb[c*EMB + (tid - NOISE)];
    __syncthreads();
    {
        const int co = tid & 255;
        const int p0 = (tid >> 8) * 24;
        float acc[25];
        #pragma unroll
        for (int i = 0; i < 25; i++) acc[i] = 0.f;
        #pragma unroll 1
        for (int k = 0; k < 150; k++){
            float x = xin[k];
            const float* wr = Wd + k*12544 + p0*256 + co;
            #pragma unroll
            for (int i = 0; i < 25; i++) acc[i] += x * wr[i*256];
        }
        #pragma unroll
        for (int i = 0; i < 25; i++){
            int j = (p0 + i)*256 + co;
            float sc = g1[j] * rsqrtf(v1[j] + BNEPS);
            float y = (acc[i] - m1[j])*sc + b1[j];
            y = (y >= 0.f) ? y : ALPHA*y;
            xt1[co*S1 + p0 + i] = y;
        }
        if (tid < EMB){
            float v = xin[NOISE + tid];
            #pragma unroll
            for (int p = 0; p < 49; p++) xt1[(256 + tid)*S1 + p] = v;
        }
    }
    __syncthreads();
    {
        const int co = tid & 255;
        const int ph = tid >> 8;
        const float* wbase = K1 + (size_t)c*25*CIN1*256 + co;
        float sc = G1[c*256 + co] * rsqrtf(V1[c*256 + co] + BNEPS);
        float mm = M1[c*256 + co], bb = B1[c*256 + co];
        if (ph == 0) conv1_full<0>(xt1, xt2, wbase, sc, mm, bb, co);
        else         conv1_full<1>(xt1, xt2, wbase, sc, mm, bb, co);
    }
    __syncthreads();
    {
        const int co = tid & 127;
        const int q  = tid >> 7;
        const float* wbase = K2 + (size_t)c*25*256*128 + co;
        float sc = G2[c*128 + co] * rsqrtf(V2[c*128 + co] + BNEPS);
        float mm = M2[c*128 + co], bb = B2[c*128 + co];
        switch (q){
            case 0: conv2_full<0>(xt2, xt3, wbase, sc, mm, bb, co); break;
            case 1: conv2_full<1>(xt2, xt3, wbase, sc, mm, bb, co); break;
            case 2: conv2_full<2>(xt2, xt3, wbase, sc, mm, bb, co); break;
            default:conv2_full<3>(xt2, xt3, wbase, sc, mm, bb, co); break;
        }
    }
    __syncthreads();
    for (int i = tid; i < 3200; i += 512) wk[i] = K3[c*3200 + i];
    __syncthreads();
    #pragma unroll 1
    for (int rep = 0; rep < 2; rep++){
        int p3 = tid + rep*512;
        if (p3 < 784){
            int i = p3 / 28, j = p3 - (p3/28)*28;
            float acc = 0.f;
            #pragma unroll
            for (int ky = 0; ky < 5; ky++){
                int t = i + ky - 3;
                if (t < 0 || (t & 1) || t >= 28) continue;
                int u = t >> 1;
                #pragma unroll
                for (int kx = 0; kx < 5; kx++){
                    int s = j + kx - 3;
                    if (s < 0 || (s & 1) || s >= 28) continue;
                    int v = s >> 1;
                    const float* xr = &xt3[(u*14 + v)*132];
                    const float* w = &wk[(ky*5 + kx)*128];
                    #pragma unroll
                    for (int cc = 0; cc < 32; cc++){
                        float4 xv = *(const float4*)&xr[4*cc];
                        float4 wv = *(const float4*)&w[4*cc];
                        acc += xv.x*wv.x + xv.y*wv.y + xv.z*wv.z + xv.w*wv.w;
                    }
                }
            }
            out[b*784 + p3] = tanhf(acc);
        }
    }
}

extern "C" void kernel_launch(void* const* d_in, const int* in_sizes, int n_in,
                              void* d_out, int out_size, void* d_ws, size_t ws_size,
                              hipStream_t stream){
    const float* noise = (const float*)d_in[0];
    const int*   labels= (const int*)  d_in[1];
    const float* emb   = (const float*)d_in[2];
    const float* Wd    = (const float*)d_in[3];
    const float* g1    = (const float*)d_in[4];
    const float* b1    = (const float*)d_in[5];
    const float* m1    = (const float*)d_in[6];
    const float* v1    = (const float*)d_in[7];
    const float* K1    = (const float*)d_in[8];
    const float* G1    = (const float*)d_in[9];
    const float* B1    = (const float*)d_in[10];
    const float* M1    = (const float*)d_in[11];
    const float* V1    = (const float*)d_in[12];
    const float* K2    = (const float*)d_in[13];
    const float* G2    = (const float*)d_in[14];
    const float* B2    = (const float*)d_in[15];
    const float* M2    = (const float*)d_in[16];
    const float* V2    = (const float*)d_in[17];
    const float* K3    = (const float*)d_in[18];
    float* outp = (float*)d_out;

    const size_t NEED = 4096 + 2*(size_t)N1*2 + 2*(size_t)N2*2 + 2*(size_t)512*49*320*2;
    int* order = (int*)d_ws;

    if (ws_size >= NEED){
        short* w1h = (short*)((char*)d_ws + 4096);
        short* w1l = w1h + N1;
        short* w2h = w1l + N1;
        short* w2l = w2h + N2;
        short* xgH = w2l + N2;
        short* xgL = xgH + (size_t)512*49*320;
        aux_k <<<1 + DENSE_BLKS + PREP_BLKS, 256, 0, stream>>>(
            noise, labels, emb, Wd, g1, b1, m1, v1, K1, K2,
            w1h, w1l, w2h, w2l, xgH, xgL, order);
        main_k <<<256, 1024, 0, stream>>>(labels, order, xgH, xgL, w1h, w1l, w2h, w2l,
                                          G1, B1, M1, V1, G2, B2, M2, V2, K3, outp);
    } else {
        // fallback: verified R5 path (needs only 2 KB ws)
        sort_k <<<1, 512, 0, stream>>>(labels, order);
        fused_k<<<512, 512, 0, stream>>>(noise, labels, emb, Wd, g1, b1, m1, v1,
                                         K1, G1, B1, M1, V1,
                                         K2, G2, B2, M2, V2, K3, order, outp);
    }
}

// Round 8
// 647.573 us; speedup vs baseline: 3.6666x; 1.0415x over previous
//
#include <hip/hip_runtime.h>

#define ALPHA 0.3f
#define BNEPS 1e-3f

typedef __attribute__((ext_vector_type(8))) short bf16x8;
typedef __attribute__((ext_vector_type(4))) float f32x4;

__device__ __forceinline__ short f2bf(float x){
    unsigned u = __float_as_uint(x);
    unsigned r = (u + 0x7FFFu + ((u >> 16) & 1u)) >> 16;   // RNE
    return (short)r;
}
__device__ __forceinline__ float bf2f(short s){
    return __uint_as_float(((unsigned)(unsigned short)s) << 16);
}

#define N1 20480000   // 250*40*256*8
#define N2 8192000    // 250*32*128*8
#define T1 2560000    // 250*40*256
#define PREP_BLKS 14000   // (T1 + N2/8)/256
#define DENSE_BLKS 1568   // 49*32

// ---------------- routing: counting sort of samples by class (512-thread, fallback) ----
__global__ void sort_k(const int* __restrict__ labels, int* __restrict__ order){
    __shared__ int cnt[10], offs[10];
    int tid = threadIdx.x;
    if (tid < 10) cnt[tid] = 0;
    __syncthreads();
    int lab = labels[tid];
    atomicAdd(&cnt[lab], 1);
    __syncthreads();
    if (tid == 0){
        int s = 0;
        for (int c = 0; c < 10; c++){ offs[c] = s; s += cnt[c]; }
    }
    __syncthreads();
    int pos = atomicAdd(&offs[lab], 1);
    order[pos] = tid;
}

// ---------------- fused aux kernel: sort (blk 0) + dense (blks 1..1568) + prep (rest) ----
// prep: fp32 -> bf16 hi/lo, B-fragment layout.
//   W1T: [ct (250)][chunk=ci/8 (40)][co (256)][ci%8]   ci in [0,320), >=306 zero
//   W2T: [ct][chunk=ci/8 (32)][co (128)][ci%8]
// dense: 150->12544 + BN1 + LReLU -> xg hi bf16 (lo not needed: conv1 is 2-term).
__global__ __launch_bounds__(256)
void aux_k(const float* __restrict__ noise, const int* __restrict__ labels,
           const float* __restrict__ emb,   const float* __restrict__ Wd,
           const float* __restrict__ g1, const float* __restrict__ b1,
           const float* __restrict__ m1, const float* __restrict__ v1,
           const float* __restrict__ K1, const float* __restrict__ K2,
           short* __restrict__ w1h, short* __restrict__ w1l,
           short* __restrict__ w2h, short* __restrict__ w2l,
           short* __restrict__ xgH, short* __restrict__ xgL,
           int* __restrict__ order){
    const int bid = blockIdx.x;
    const int tid = threadIdx.x;

    if (bid == 0){
        // ---- counting sort of 512 labels with 256 threads ----
        __shared__ int cnt[10], offs[10];
        if (tid < 10) cnt[tid] = 0;
        __syncthreads();
        int l0 = labels[tid], l1 = labels[tid + 256];
        atomicAdd(&cnt[l0], 1);
        atomicAdd(&cnt[l1], 1);
        __syncthreads();
        if (tid == 0){
            int s = 0;
            for (int c = 0; c < 10; c++){ offs[c] = s; s += cnt[c]; }
        }
        __syncthreads();
        int p0 = atomicAdd(&offs[l0], 1);
        order[p0] = tid;
        int p1 = atomicAdd(&offs[l1], 1);
        order[p1] = tid + 256;
        return;
    }

    if (bid <= DENSE_BLKS){
        // ---- dense: one (q, 16-sample tile) per block ----
        __shared__ float xs[16][152];
        const int b2 = bid - 1;
        const int q  = b2 % 49;
        const int st = b2 / 49;
        for (int i = tid; i < 16*150; i += 256){
            int ss = i / 150, k = i % 150;
            int b = st*16 + ss;
            xs[ss][k] = (k < 100) ? noise[b*100 + k] : emb[labels[b]*50 + (k-100)];
        }
        __syncthreads();
        const int co = tid;
        const int j = q*256 + co;
        float acc[16];
        #pragma unroll
        for (int ss = 0; ss < 16; ss++) acc[ss] = 0.f;
        #pragma unroll 2
        for (int k = 0; k < 150; k++){
            float w = Wd[k*12544 + j];
            #pragma unroll
            for (int ss = 0; ss < 16; ss++)
                acc[ss] += xs[ss][k] * w;
        }
        float sc = g1[j] * rsqrtf(v1[j] + BNEPS);
        float mm = m1[j], bb = b1[j];
        #pragma unroll
        for (int ss = 0; ss < 16; ss++){
            float y = (acc[ss] - mm)*sc + bb;
            y = (y >= 0.f) ? y : ALPHA*y;
            size_t o = ((size_t)(st*16 + ss)*49 + q)*320 + co;
            xgH[o] = f2bf(y);
        }
        {
            int ss = tid >> 4, cg = tid & 15;
            #pragma unroll
            for (int cj = 0; cj < 4; cj++){
                int col = 256 + cg*4 + cj;
                float v = (col < 306) ? xs[ss][100 + col - 256] : 0.f;
                size_t o = ((size_t)(st*16 + ss)*49 + q)*320 + col;
                xgH[o] = f2bf(v);
            }
        }
        return;
    }

    // ---- prep ----
    int t = (bid - 1 - DENSE_BLKS) * 256 + tid;
    if (t < T1){
        int co = t & 255;
        int ch = (t >> 8) % 40;
        int ct = (t >> 8) / 40;
        bf16x8 h, l;
        #pragma unroll
        for (int j = 0; j < 8; j++){
            int ci = ch*8 + j;
            float w = (ci < 306) ? K1[((size_t)ct*306 + ci)*256 + co] : 0.f;
            short hh = f2bf(w);
            h[j] = hh;
            l[j] = f2bf(w - bf2f(hh));
        }
        size_t dst = (size_t)t * 8;
        *(bf16x8*)&w1h[dst] = h;
        *(bf16x8*)&w1l[dst] = l;
    } else {
        int tt = t - T1;
        int co = tt & 127;
        int ch = (tt >> 7) & 31;
        int ct = tt >> 12;
        bf16x8 h, l;
        #pragma unroll
        for (int j = 0; j < 8; j++){
            int ci = ch*8 + j;
            float w = K2[((size_t)ct*256 + ci)*128 + co];
            short hh = f2bf(w);
            h[j] = hh;
            l[j] = f2bf(w - bf2f(hh));
        }
        size_t dst = (size_t)tt * 8;
        *(bf16x8*)&w2h[dst] = h;
        *(bf16x8*)&w2l[dst] = l;
    }
}

// ---------------- main: conv1 + conv2 both 2-term MFMA + conv3 (VALU), 2 samples/block ----
// 2-term: x ~ xh only (A-residual dropped, rel err ~2^-9 per layer), W = wh + wl exact to 2^-16.
// 1024 threads = 16 waves -> 4 waves/SIMD at 1 block/CU.
__global__ __launch_bounds__(1024, 1)
void main_k(const int* __restrict__ labels, const int* __restrict__ order,
            const short* __restrict__ xgH, const short* __restrict__ xgL,
            const short* __restrict__ w1h, const short* __restrict__ w1l,
            const short* __restrict__ w2h, const short* __restrict__ w2l,
            const float* __restrict__ G1, const float* __restrict__ B1,
            const float* __restrict__ M1, const float* __restrict__ V1,
            const float* __restrict__ G2, const float* __restrict__ B2,
            const float* __restrict__ M2, const float* __restrict__ V2,
            const float* __restrict__ K3, float* __restrict__ out){
    __shared__ __align__(16) short smem[65600];          // 131,200 B
    __shared__ int binfo[4];
    const int tid = threadIdx.x;
    const int idx = ((blockIdx.x & 7) << 5) | (blockIdx.x >> 3);   // XCD swizzle, 256 blocks
    if (tid < 2){
        int b = order[2*idx + tid];
        binfo[tid] = b;
        binfo[2 + tid] = labels[b];
    }
    {   // zero LDS (padding rows rely on this)
        uint4 z; z.x = z.y = z.z = z.w = 0;
        uint4* p = (uint4*)smem;
        for (int i = tid; i < 8200; i += 1024) p[i] = z;
    }
    __syncthreads();
    // copy xcat rows (s,q): 98 rows x 40 uint4 (hi plane only; conv1 is 2-term)
    for (int i = tid; i < 3920; i += 1024){
        int t = i % 40, w = i / 40;
        int q = w % 49, s = w / 49;
        const short* src = xgH + ((size_t)binfo[s]*49 + q)*320;
        *(uint4*)&smem[(s*2)*16400 + q*328 + t*8] = *(const uint4*)&src[t*8];
    }
    __syncthreads();

    const int lane = tid & 63, wid = tid >> 6;
    const int l31 = lane & 31, half = lane >> 5;
    typedef __attribute__((ext_vector_type(16))) float f32x16;

    // ================= conv1: 7x7x306 -> 7x7x256 (s=1, pads 2,2), 32x32x16 MFMA, 2-term ==========
    {
        const int s = wid & 1, kv = (wid >> 1) & 1, nq = wid >> 2;   // nq 0..3
        const int c = binfo[2 + s];
        const short* xh = smem + (s*2 + 0)*16400;
        const int kvb = kv*160;
        f32x16 acc[2][2];
        #pragma unroll
        for (int mi = 0; mi < 2; mi++)
            #pragma unroll
            for (int ni = 0; ni < 2; ni++)
                #pragma unroll
                for (int r = 0; r < 16; r++) acc[mi][ni][r] = 0.f;
        int py[2], px[2], pok[2];
        #pragma unroll
        for (int mi = 0; mi < 2; mi++){
            int p = mi*32 + l31;
            py[mi] = p/7; px[mi] = p%7; pok[mi] = (p < 49);
        }
        #pragma unroll 1
        for (int tap = 0; tap < 25; tap++){
            int ky = tap/5, kx = tap%5;
            int aoff[2];
            #pragma unroll
            for (int mi = 0; mi < 2; mi++){
                int iy = py[mi] + ky - 2, ix = px[mi] + kx - 2;
                bool ok = pok[mi] & (iy >= 0) & (iy < 7) & (ix >= 0) & (ix < 7);
                int q = ok ? iy*7 + ix : 49;             // row 49 = zeros
                aoff[mi] = q*328 + kvb + half*8;
            }
            size_t tapbase = ((size_t)(c*25 + tap))*81920;   // 40*256*8
            const short *pbh[2], *pbl[2];
            #pragma unroll
            for (int ni = 0; ni < 2; ni++){
                int co = nq*64 + ni*32 + l31;
                size_t off = tapbase + ((size_t)((kv*20 + half)*256 + co))*8;
                pbh[ni] = w1h + off; pbl[ni] = w1l + off;
            }
            #pragma unroll 2
            for (int ks = 0; ks < 10; ks++){
                bf16x8 Ah[2], Bh[2], Bl[2];
                #pragma unroll
                for (int mi = 0; mi < 2; mi++)
                    Ah[mi] = *(const bf16x8*)&xh[aoff[mi] + ks*16];
                #pragma unroll
                for (int ni = 0; ni < 2; ni++){
                    Bh[ni] = *(const bf16x8*)&pbh[ni][ks*4096];
                    Bl[ni] = *(const bf16x8*)&pbl[ni][ks*4096];
                }
                __builtin_amdgcn_s_setprio(1);
                #pragma unroll
                for (int mi = 0; mi < 2; mi++)
                    #pragma unroll
                    for (int ni = 0; ni < 2; ni++){
                        acc[mi][ni] = __builtin_amdgcn_mfma_f32_32x32x16_bf16(Ah[mi], Bh[ni], acc[mi][ni], 0, 0, 0);
                        acc[mi][ni] = __builtin_amdgcn_mfma_f32_32x32x16_bf16(Ah[mi], Bl[ni], acc[mi][ni], 0, 0, 0);
                    }
                __builtin_amdgcn_s_setprio(0);
            }
        }
        __syncthreads();   // all conv1 LDS reads complete -> region becomes f32 scratch
        // 2-way K-combine through LDS: kv=1 writes partials, kv=0 adds.
        float* scr = (float*)smem;
        const int g = s*4 + nq;                          // 8 groups x 16 KB
        if (kv){
            #pragma unroll
            for (int t4 = 0; t4 < 4; t4++){
                const int mi = t4 >> 1, ni = t4 & 1;
                #pragma unroll
                for (int rq = 0; rq < 4; rq++){
                    f32x4 v;
                    v[0] = acc[mi][ni][rq*4+0]; v[1] = acc[mi][ni][rq*4+1];
                    v[2] = acc[mi][ni][rq*4+2]; v[3] = acc[mi][ni][rq*4+3];
                    *(f32x4*)&scr[g*4096 + (t4*4 + rq)*256 + lane*4] = v;
                }
            }
        }
        __syncthreads();
        if (!kv){
            #pragma unroll
            for (int t4 = 0; t4 < 4; t4++){
                const int mi = t4 >> 1, ni = t4 & 1;
                #pragma unroll
                for (int rq = 0; rq < 4; rq++){
                    f32x4 v = *(const f32x4*)&scr[g*4096 + (t4*4 + rq)*256 + lane*4];
                    acc[mi][ni][rq*4+0] += v[0]; acc[mi][ni][rq*4+1] += v[1];
                    acc[mi][ni][rq*4+2] += v[2]; acc[mi][ni][rq*4+3] += v[3];
                }
            }
        }
        __syncthreads();   // scratch reads complete -> region becomes conv2 input
        if (!kv){
            // epilogue: BN + LReLU -> conv2-in (hi only; conv2 is 2-term)
            const int co = nq*64;
            float sc[2], mm[2], bb[2];
            #pragma unroll
            for (int ni = 0; ni < 2; ni++){
                int cc = co + ni*32 + l31;
                sc[ni] = G1[c*256 + cc] * rsqrtf(V1[c*256 + cc] + BNEPS);
                mm[ni] = M1[c*256 + cc];
                bb[ni] = B1[c*256 + cc];
            }
            short* yh = smem + (s*2 + 0)*13200;
            yh[49*264 + nq*64 + (lane & 31)] = 0;  yh[49*264 + nq*64 + 32 + (lane & 31)] = 0;
            #pragma unroll
            for (int mi = 0; mi < 2; mi++)
                #pragma unroll
                for (int ni = 0; ni < 2; ni++)
                    #pragma unroll
                    for (int r = 0; r < 16; r++){
                        int p = mi*32 + (r & 3) + 8*(r >> 2) + 4*half;
                        if (p < 49){
                            float y = (acc[mi][ni][r] - mm[ni])*sc[ni] + bb[ni];
                            y = (y >= 0.f) ? y : ALPHA*y;
                            int o = p*264 + co + ni*32 + l31;
                            yh[o] = f2bf(y);
                        }
                    }
        }
    }
    __syncthreads();

    // ================= conv2: 7x7x256 -> 14x14x128 (s=2, pads 3,2), parity split, 2-term =========
    {
        const int s = wid & 1, par = (wid >> 1) & 3, nh = wid >> 3;
        const int pi = par >> 1, pj = par & 1;
        const int c = binfo[2 + s];
        const short* xh = smem + (s*2 + 0)*13200;
        f32x16 acc[2][2];
        #pragma unroll
        for (int mi = 0; mi < 2; mi++)
            #pragma unroll
            for (int ni = 0; ni < 2; ni++)
                #pragma unroll
                for (int r = 0; r < 16; r++) acc[mi][ni][r] = 0.f;
        int py[2], px[2], pok[2];
        #pragma unroll
        for (int mi = 0; mi < 2; mi++){
            int p = mi*32 + l31;
            py[mi] = p/7; px[mi] = p%7; pok[mi] = (p < 49);
        }
        const int nky = pi ? 3 : 2, kyb = pi ? 0 : 1;
        const int nkx = pj ? 3 : 2, kxb = pj ? 0 : 1;
        #pragma unroll 1
        for (int ty = 0; ty < nky; ty++){
            int ky = kyb + 2*ty;
            int dy = (pi + ky - 3) / 2;
            #pragma unroll 1
            for (int tx = 0; tx < nkx; tx++){
                int kx = kxb + 2*tx;
                int dx = (pj + kx - 3) / 2;
                int tap = ky*5 + kx;
                int aoff[2];
                #pragma unroll
                for (int mi = 0; mi < 2; mi++){
                    int u = py[mi] + dy, v = px[mi] + dx;
                    bool ok = pok[mi] & (u >= 0) & (u < 7) & (v >= 0) & (v < 7);
                    int q = ok ? u*7 + v : 49;
                    aoff[mi] = q*264 + half*8;
                }
                size_t tapbase = ((size_t)(c*25 + tap))*32768;   // 32*128*8
                const short *pbh[2], *pbl[2];
                #pragma unroll
                for (int ni = 0; ni < 2; ni++){
                    int co = nh*64 + ni*32 + l31;
                    size_t off = tapbase + ((size_t)(half*128 + co))*8;
                    pbh[ni] = w2h + off; pbl[ni] = w2l + off;
                }
                #pragma unroll 2
                for (int ks = 0; ks < 16; ks++){
                    bf16x8 Ah[2], Bh[2], Bl[2];
                    #pragma unroll
                    for (int mi = 0; mi < 2; mi++)
                        Ah[mi] = *(const bf16x8*)&xh[aoff[mi] + ks*16];
                    #pragma unroll
                    for (int ni = 0; ni < 2; ni++){
                        Bh[ni] = *(const bf16x8*)&pbh[ni][ks*2048];
                        Bl[ni] = *(const bf16x8*)&pbl[ni][ks*2048];
                    }
                    __builtin_amdgcn_s_setprio(1);
                    #pragma unroll
                    for (int mi = 0; mi < 2; mi++)
                        #pragma unroll
                        for (int ni = 0; ni < 2; ni++){
                            acc[mi][ni] = __builtin_amdgcn_mfma_f32_32x32x16_bf16(Ah[mi], Bh[ni], acc[mi][ni], 0, 0, 0);
                            acc[mi][ni] = __builtin_amdgcn_mfma_f32_32x32x16_bf16(Ah[mi], Bl[ni], acc[mi][ni], 0, 0, 0);
                        }
                    __builtin_amdgcn_s_setprio(0);
                }
            }
        }
        __syncthreads();   // all conv2 LDS reads complete; smem free
        float sc[2], mm[2], bb[2];
        #pragma unroll
        for (int ni = 0; ni < 2; ni++){
            int co = nh*64 + ni*32 + l31;
            sc[ni] = G2[c*128 + co] * rsqrtf(V2[c*128 + co] + BNEPS);
            mm[ni] = M2[c*128 + co];
            bb[ni] = B2[c*128 + co];
        }
        float* h2f = (float*)smem;          // 196*132
        float* wk3 = (float*)smem + 25872;  // 3200
        #pragma unroll 1
        for (int sp = 0; sp < 2; sp++){
            if (s == sp){
                #pragma unroll
                for (int mi = 0; mi < 2; mi++)
                    #pragma unroll
                    for (int ni = 0; ni < 2; ni++)
                        #pragma unroll
                        for (int r = 0; r < 16; r++){
                            int p = mi*32 + (r & 3) + 8*(r >> 2) + 4*half;
                            if (p < 49){
                                int oy = p / 7, ox = p % 7;
                                int q2 = (2*oy + pi)*14 + (2*ox + pj);
                                float y = (acc[mi][ni][r] - mm[ni])*sc[ni] + bb[ni];
                                y = (y >= 0.f) ? y : ALPHA*y;
                                h2f[q2*132 + nh*64 + ni*32 + l31] = y;
                            }
                        }
            }
            int cs = binfo[2 + sp];
            for (int i = tid; i < 3200; i += 1024) wk3[i] = K3[cs*3200 + i];
            __syncthreads();
            // conv3: 14x14x128 -> 28x28x1, s=2, pads (3,2), tanh
            int p3 = tid;
            if (p3 < 784){
                int oi = p3 / 28, oj = p3 % 28;
                float a3 = 0.f;
                #pragma unroll
                for (int ky = 0; ky < 5; ky++){
                    int t = oi + ky - 3;
                    if (t < 0 || (t & 1) || t >= 28) continue;
                    int u = t >> 1;
                    #pragma unroll
                    for (int kx = 0; kx < 5; kx++){
                        int ss2 = oj + kx - 3;
                        if (ss2 < 0 || (ss2 & 1) || ss2 >= 28) continue;
                        int v = ss2 >> 1;
                        const float* xr = &h2f[(u*14 + v)*132];
                        const float* w = &wk3[(ky*5 + kx)*128];
                        #pragma unroll
                        for (int cc = 0; cc < 32; cc++){
                            float4 xv = *(const float4*)&xr[4*cc];
                            float4 wv = *(const float4*)&w[4*cc];
                            a3 += xv.x*wv.x + xv.y*wv.y + xv.z*wv.z + xv.w*wv.w;
                        }
                    }
                }
                out[binfo[sp]*784 + p3] = tanhf(a3);
            }
            __syncthreads();   // before next sp overwrites h2f
        }
    }
}

// =======================================================================================
// Fallback path (verified R5 kernel) — used when ws_size is too small for the MFMA path.
// =======================================================================================
#define NOISE 100
#define EMB   50
#define CIN1  306
#define S1    52

template<int PH>
__device__ __forceinline__ void conv1_full(const float* __restrict__ xt1, float* __restrict__ xt2,
                                           const float* __restrict__ wbase,
                                           float sc, float mm, float bb, int co){
    constexpr int OY0 = PH ? 4 : 0;
    constexpr int NOY = PH ? 3 : 4;
    float acc[NOY*7];
    #pragma unroll
    for (int i = 0; i < NOY*7; i++) acc[i] = 0.f;
    #pragma unroll 1
    for (int ci = 0; ci < CIN1; ci++){
        float xr[49];
        #pragma unroll
        for (int r = 0; r < 12; r++) *(float4*)&xr[4*r] = *(const float4*)&xt1[ci*S1 + 4*r];
        xr[48] = xt1[ci*S1 + 48];
        const float* wci = wbase + ci*256;
        #pragma unroll
        for (int ky = 0; ky < 5; ky++)
            #pragma unroll
            for (int kx = 0; kx < 5; kx++){
                float w = wci[(ky*5 + kx)*CIN1*256];
                #pragma unroll
                for (int oy = OY0; oy < OY0 + NOY; oy++){
                    int iy = oy + ky - 2;
                    if (iy < 0 || iy >= 7) continue;
                    #pragma unroll
                    for (int ox = 0; ox < 7; ox++){
                        int ix = ox + kx - 2;
                        if (ix < 0 || ix >= 7) continue;
                        acc[(oy - OY0)*7 + ox] += xr[iy*7 + ix] * w;
                    }
                }
            }
    }
    #pragma unroll
    for (int i = 0; i < NOY*7; i++){
        float y = (acc[i] - mm)*sc + bb;
        xt2[co*S1 + OY0*7 + i] = (y >= 0.f) ? y : ALPHA*y;
    }
}

template<int Q>
__device__ __forceinline__ void conv2_full(const float* __restrict__ xt2, float* __restrict__ xt3,
                                           const float* __restrict__ wbase,
                                           float sc, float mm, float bb, int co){
    float acc[49];
    #pragma unroll
    for (int i = 0; i < 49; i++) acc[i] = 0.f;
    #pragma unroll 1
    for (int ci = 0; ci < 256; ci++){
        float xr[49];
        #pragma unroll
        for (int r = 0; r < 12; r++) *(float4*)&xr[4*r] = *(const float4*)&xt2[ci*S1 + 4*r];
        xr[48] = xt2[ci*S1 + 48];
        const float* wci = wbase + ci*128;
        #pragma unroll
        for (int ky = 0; ky < 5; ky++)
            #pragma unroll
            for (int kx = 0; kx < 5; kx++){
                float w = wci[(ky*5 + kx)*256*128];
                #pragma unroll
                for (int ii = 0; ii < 49; ii++){
                    int p2 = Q*49 + ii;
                    int i = p2 / 14, j = p2 % 14;
                    int t = i + ky - 3, s = j + kx - 3;
                    if (t < 0 || (t & 1) || t >= 14) continue;
                    if (s < 0 || (s & 1) || s >= 14) continue;
                    acc[ii] += xr[(t >> 1)*7 + (s >> 1)] * w;
                }
            }
    }
    #pragma unroll
    for (int ii = 0; ii < 49; ii++){
        int p2 = Q*49 + ii;
        float y = (acc[ii] - mm)*sc + bb;
        xt3[p2*132 + co] = (y >= 0.f) ? y : ALPHA*y;
    }
}

__global__ __launch_bounds__(512, 2)
void fused_k(const float* __restrict__ noise, const int* __restrict__ labels,
             const float* __restrict__ emb,   const float* __restrict__ Wd,
             const float* __restrict__ g1,    const float* __restrict__ b1,
             const float* __restrict__ m1,    const float* __restrict__ v1,
             const float* __restrict__ K1,
             const float* __restrict__ G1, const float* __restrict__ B1,
             const float* __restrict__ M1, const float* __restrict__ V1,
             const float* __restrict__ K2,
             const float* __restrict__ G2, const float* __restrict__ B2,
             const float* __restrict__ M2, const float* __restrict__ V2,
             const float* __restrict__ K3,
             const int* __restrict__ order,
             float* __restrict__ out){
    __shared__ __align__(16) unsigned char smem[53248 + 103488];
    __shared__ float xin[152];
    float* xt2 = (float*)smem;
    float* wk  = (float*)smem;
    float* xt1 = (float*)(smem + 53248);
    float* xt3 = (float*)(smem + 53248);

    const int tid = threadIdx.x;
    const int idx = ((blockIdx.x & 7) << 6) | (blockIdx.x >> 3);
    const int b = order[idx];
    const int c = labels[b];

    if (tid < 150)
        xin[tid] = (tid < NOISE) ? noise[b*NOISE + tid] : emb[c*EMB + (tid - NOISE)];
    __syncthreads();
    {
        const int co = tid & 255;
        const int p0 = (tid >> 8) * 24;
        float acc[25];
        #pragma unroll
        for (int i = 0; i < 25; i++) acc[i] = 0.f;
        #pragma unroll 1
        for (int k = 0; k < 150; k++){
            float x = xin[k];
            const float* wr = Wd + k*12544 + p0*256 + co;
            #pragma unroll
            for (int i = 0; i < 25; i++) acc[i] += x * wr[i*256];
        }
        #pragma unroll
        for (int i = 0; i < 25; i++){
            int j = (p0 + i)*256 + co;
            float sc = g1[j] * rsqrtf(v1[j] + BNEPS);
            float y = (acc[i] - m1[j])*sc + b1[j];
            y = (y >= 0.f) ? y : ALPHA*y;
            xt1[co*S1 + p0 + i] = y;
        }
        if (tid < EMB){
            float v = xin[NOISE + tid];
            #pragma unroll
            for (int p = 0; p < 49; p++) xt1[(256 + tid)*S1 + p] = v;
        }
    }
    __syncthreads();
    {
        const int co = tid & 255;
        const int ph = tid >> 8;
        const float* wbase = K1 + (size_t)c*25*CIN1*256 + co;
        float sc = G1[c*256 + co] * rsqrtf(V1[c*256 + co] + BNEPS);
        float mm = M1[c*256 + co], bb = B1[c*256 + co];
        if (ph == 0) conv1_full<0>(xt1, xt2, wbase, sc, mm, bb, co);
        else         conv1_full<1>(xt1, xt2, wbase, sc, mm, bb, co);
    }
    __syncthreads();
    {
        const int co = tid & 127;
        const int q  = tid >> 7;
        const float* wbase = K2 + (size_t)c*25*256*128 + co;
        float sc = G2[c*128 + co] * rsqrtf(V2[c*128 + co] + BNEPS);
        float mm = M2[c*128 + co], bb = B2[c*128 + co];
        switch (q){
            case 0: conv2_full<0>(xt2, xt3, wbase, sc, mm, bb, co); break;
            case 1: conv2_full<1>(xt2, xt3, wbase, sc, mm, bb, co); break;
            case 2: conv2_full<2>(xt2, xt3, wbase, sc, mm, bb, co); break;
            default:conv2_full<3>(xt2, xt3, wbase, sc, mm, bb, co); break;
        }
    }
    __syncthreads();
    for (int i = tid; i < 3200; i += 512) wk[i] = K3[c*3200 + i];
    __syncthreads();
    #pragma unroll 1
    for (int rep = 0; rep < 2; rep++){
        int p3 = tid + rep*512;
        if (p3 < 784){
            int i = p3 / 28, j = p3 - (p3/28)*28;
            float acc = 0.f;
            #pragma unroll
            for (int ky = 0; ky < 5; ky++){
                int t = i + ky - 3;
                if (t < 0 || (t & 1) || t >= 28) continue;
                int u = t >> 1;
                #pragma unroll
                for (int kx = 0; kx < 5; kx++){
                    int s = j + kx - 3;
                    if (s < 0 || (s & 1) || s >= 28) continue;
                    int v = s >> 1;
                    const float* xr = &xt3[(u*14 + v)*132];
                    const float* w = &wk[(ky*5 + kx)*128];
                    #pragma unroll
                    for (int cc = 0; cc < 32; cc++){
                        float4 xv = *(const float4*)&xr[4*cc];
                        float4 wv = *(const float4*)&w[4*cc];
                        acc += xv.x*wv.x + xv.y*wv.y + xv.z*wv.z + xv.w*wv.w;
                    }
                }
            }
            out[b*784 + p3] = tanhf(acc);
        }
    }
}

extern "C" void kernel_launch(void* const* d_in, const int* in_sizes, int n_in,
                              void* d_out, int out_size, void* d_ws, size_t ws_size,
                              hipStream_t stream){
    const float* noise = (const float*)d_in[0];
    const int*   labels= (const int*)  d_in[1];
    const float* emb   = (const float*)d_in[2];
    const float* Wd    = (const float*)d_in[3];
    const float* g1    = (const float*)d_in[4];
    const float* b1    = (const float*)d_in[5];
    const float* m1    = (const float*)d_in[6];
    const float* v1    = (const float*)d_in[7];
    const float* K1    = (const float*)d_in[8];
    const float* G1    = (const float*)d_in[9];
    const float* B1    = (const float*)d_in[10];
    const float* M1    = (const float*)d_in[11];
    const float* V1    = (const float*)d_in[12];
    const float* K2    = (const float*)d_in[13];
    const float* G2    = (const float*)d_in[14];
    const float* B2    = (const float*)d_in[15];
    const float* M2    = (const float*)d_in[16];
    const float* V2    = (const float*)d_in[17];
    const float* K3    = (const float*)d_in[18];
    float* outp = (float*)d_out;

    const size_t NEED = 4096 + 2*(size_t)N1*2 + 2*(size_t)N2*2 + 2*(size_t)512*49*320*2;
    int* order = (int*)d_ws;

    if (ws_size >= NEED){
        short* w1h = (short*)((char*)d_ws + 4096);
        short* w1l = w1h + N1;
        short* w2h = w1l + N1;
        short* w2l = w2h + N2;
        short* xgH = w2l + N2;
        short* xgL = xgH + (size_t)512*49*320;
        aux_k <<<1 + DENSE_BLKS + PREP_BLKS, 256, 0, stream>>>(
            noise, labels, emb, Wd, g1, b1, m1, v1, K1, K2,
            w1h, w1l, w2h, w2l, xgH, xgL, order);
        main_k <<<256, 1024, 0, stream>>>(labels, order, xgH, xgL, w1h, w1l, w2h, w2l,
                                          G1, B1, M1, V1, G2, B2, M2, V2, K3, outp);
    } else {
        // fallback: verified R5 path (needs only 2 KB ws)
        sort_k <<<1, 512, 0, stream>>>(labels, order);
        fused_k<<<512, 512, 0, stream>>>(noise, labels, emb, Wd, g1, b1, m1, v1,
                                         K1, G1, B1, M1, V1,
                                         K2, G2, B2, M2, V2, K3, order, outp);
    }
}

// Round 10
// 502.489 us; speedup vs baseline: 4.7252x; 1.2887x over previous
//
#include <hip/hip_runtime.h>

#define ALPHA 0.3f
#define BNEPS 1e-3f

typedef __attribute__((ext_vector_type(8))) short bf16x8;
typedef __attribute__((ext_vector_type(4))) float f32x4;

__device__ __forceinline__ short f2bf(float x){
    unsigned u = __float_as_uint(x);
    unsigned r = (u + 0x7FFFu + ((u >> 16) & 1u)) >> 16;   // RNE
    return (short)r;
}
__device__ __forceinline__ float bf2f(short s){
    return __uint_as_float(((unsigned)(unsigned short)s) << 16);
}

#define N1 20480000   // 250*40*256*8
#define N2 8192000    // 250*32*128*8
#define T1 2560000    // 250*40*256
#define PREP_BLKS 14000   // (T1 + N2/8)/256
#define DENSE_BLKS 1568   // 49*32

// ---------------- routing: counting sort of samples by class (512-thread, fallback) ----
__global__ void sort_k(const int* __restrict__ labels, int* __restrict__ order){
    __shared__ int cnt[10], offs[10];
    int tid = threadIdx.x;
    if (tid < 10) cnt[tid] = 0;
    __syncthreads();
    int lab = labels[tid];
    atomicAdd(&cnt[lab], 1);
    __syncthreads();
    if (tid == 0){
        int s = 0;
        for (int c = 0; c < 10; c++){ offs[c] = s; s += cnt[c]; }
    }
    __syncthreads();
    int pos = atomicAdd(&offs[lab], 1);
    order[pos] = tid;
}

// ---------------- fused aux kernel: sort (blk 0) + dense (blks 1..1568) + prep (rest) ----
// prep: fp32 -> RNE bf16 (single term), B-fragment layout.
//   W1T: [ct (250)][chunk=ci/8 (40)][co (256)][ci%8]   ci in [0,320), >=306 zero
//   W2T: [ct][chunk=ci/8 (32)][co (128)][ci%8]
// dense: 150->12544 + BN1 + LReLU -> xg bf16.
__global__ __launch_bounds__(256)
void aux_k(const float* __restrict__ noise, const int* __restrict__ labels,
           const float* __restrict__ emb,   const float* __restrict__ Wd,
           const float* __restrict__ g1, const float* __restrict__ b1,
           const float* __restrict__ m1, const float* __restrict__ v1,
           const float* __restrict__ K1, const float* __restrict__ K2,
           short* __restrict__ w1h, short* __restrict__ w2h,
           short* __restrict__ xgH,
           int* __restrict__ order){
    const int bid = blockIdx.x;
    const int tid = threadIdx.x;

    if (bid == 0){
        // ---- counting sort of 512 labels with 256 threads ----
        __shared__ int cnt[10], offs[10];
        if (tid < 10) cnt[tid] = 0;
        __syncthreads();
        int l0 = labels[tid], l1 = labels[tid + 256];
        atomicAdd(&cnt[l0], 1);
        atomicAdd(&cnt[l1], 1);
        __syncthreads();
        if (tid == 0){
            int s = 0;
            for (int c = 0; c < 10; c++){ offs[c] = s; s += cnt[c]; }
        }
        __syncthreads();
        int p0 = atomicAdd(&offs[l0], 1);
        order[p0] = tid;
        int p1 = atomicAdd(&offs[l1], 1);
        order[p1] = tid + 256;
        return;
    }

    if (bid <= DENSE_BLKS){
        // ---- dense: one (q, 16-sample tile) per block ----
        __shared__ float xs[16][152];
        const int b2 = bid - 1;
        const int q  = b2 % 49;
        const int st = b2 / 49;
        for (int i = tid; i < 16*150; i += 256){
            int ss = i / 150, k = i % 150;
            int b = st*16 + ss;
            xs[ss][k] = (k < 100) ? noise[b*100 + k] : emb[labels[b]*50 + (k-100)];
        }
        __syncthreads();
        const int co = tid;
        const int j = q*256 + co;
        float acc[16];
        #pragma unroll
        for (int ss = 0; ss < 16; ss++) acc[ss] = 0.f;
        #pragma unroll 2
        for (int k = 0; k < 150; k++){
            float w = Wd[k*12544 + j];
            #pragma unroll
            for (int ss = 0; ss < 16; ss++)
                acc[ss] += xs[ss][k] * w;
        }
        float sc = g1[j] * rsqrtf(v1[j] + BNEPS);
        float mm = m1[j], bb = b1[j];
        #pragma unroll
        for (int ss = 0; ss < 16; ss++){
            float y = (acc[ss] - mm)*sc + bb;
            y = (y >= 0.f) ? y : ALPHA*y;
            size_t o = ((size_t)(st*16 + ss)*49 + q)*320 + co;
            xgH[o] = f2bf(y);
        }
        {
            int ss = tid >> 4, cg = tid & 15;
            #pragma unroll
            for (int cj = 0; cj < 4; cj++){
                int col = 256 + cg*4 + cj;
                float v = (col < 306) ? xs[ss][100 + col - 256] : 0.f;
                size_t o = ((size_t)(st*16 + ss)*49 + q)*320 + col;
                xgH[o] = f2bf(v);
            }
        }
        return;
    }

    // ---- prep (single RNE bf16 term) ----
    int t = (bid - 1 - DENSE_BLKS) * 256 + tid;
    if (t < T1){
        int co = t & 255;
        int ch = (t >> 8) % 40;
        int ct = (t >> 8) / 40;
        bf16x8 h;
        #pragma unroll
        for (int j = 0; j < 8; j++){
            int ci = ch*8 + j;
            float w = (ci < 306) ? K1[((size_t)ct*306 + ci)*256 + co] : 0.f;
            h[j] = f2bf(w);
        }
        *(bf16x8*)&w1h[(size_t)t * 8] = h;
    } else {
        int tt = t - T1;
        int co = tt & 127;
        int ch = (tt >> 7) & 31;
        int ct = tt >> 12;
        bf16x8 h;
        #pragma unroll
        for (int j = 0; j < 8; j++){
            int ci = ch*8 + j;
            float w = K2[((size_t)ct*256 + ci)*128 + co];
            h[j] = f2bf(w);
        }
        *(bf16x8*)&w2h[(size_t)tt * 8] = h;
    }
}

// ---------------- main: conv1 + conv2 single-term MFMA + conv3 (VALU), 2 samples/block ----
// Single-term: x and W both RNE bf16 (rel err ~2^-9 each).
// 1024 threads = 16 waves -> 4 waves/SIMD at 1 block/CU.
__global__ __launch_bounds__(1024, 1)
void main_k(const int* __restrict__ labels, const int* __restrict__ order,
            const short* __restrict__ xgH,
            const short* __restrict__ w1h, const short* __restrict__ w2h,
            const float* __restrict__ G1, const float* __restrict__ B1,
            const float* __restrict__ M1, const float* __restrict__ V1,
            const float* __restrict__ G2, const float* __restrict__ B2,
            const float* __restrict__ M2, const float* __restrict__ V2,
            const float* __restrict__ K3, float* __restrict__ out){
    __shared__ __align__(16) short smem[65600];          // 131,200 B
    __shared__ int binfo[4];
    const int tid = threadIdx.x;
    const int idx = ((blockIdx.x & 7) << 5) | (blockIdx.x >> 3);   // XCD swizzle, 256 blocks
    if (tid < 2){
        int b = order[2*idx + tid];
        binfo[tid] = b;
        binfo[2 + tid] = labels[b];
    }
    {   // zero LDS (padding rows rely on this)
        uint4 z; z.x = z.y = z.z = z.w = 0;
        uint4* p = (uint4*)smem;
        for (int i = tid; i < 8200; i += 1024) p[i] = z;
    }
    __syncthreads();
    // copy xcat rows (s,q): 98 rows x 40 uint4
    for (int i = tid; i < 3920; i += 1024){
        int t = i % 40, w = i / 40;
        int q = w % 49, s = w / 49;
        const short* src = xgH + ((size_t)binfo[s]*49 + q)*320;
        *(uint4*)&smem[(s*2)*16400 + q*328 + t*8] = *(const uint4*)&src[t*8];
    }
    __syncthreads();

    const int lane = tid & 63, wid = tid >> 6;
    const int l31 = lane & 31, half = lane >> 5;
    typedef __attribute__((ext_vector_type(16))) float f32x16;

    // ================= conv1: 7x7x306 -> 7x7x256 (s=1, pads 2,2), 32x32x16 MFMA, 1-term =========
    {
        const int s = wid & 1, kv = (wid >> 1) & 1, nq = wid >> 2;   // nq 0..3
        const int c = binfo[2 + s];
        const short* xh = smem + (s*2 + 0)*16400;
        const int kvb = kv*160;
        f32x16 acc[2][2];
        #pragma unroll
        for (int mi = 0; mi < 2; mi++)
            #pragma unroll
            for (int ni = 0; ni < 2; ni++)
                #pragma unroll
                for (int r = 0; r < 16; r++) acc[mi][ni][r] = 0.f;
        int py[2], px[2], pok[2];
        #pragma unroll
        for (int mi = 0; mi < 2; mi++){
            int p = mi*32 + l31;
            py[mi] = p/7; px[mi] = p%7; pok[mi] = (p < 49);
        }
        #pragma unroll 1
        for (int tap = 0; tap < 25; tap++){
            int ky = tap/5, kx = tap%5;
            int aoff[2];
            #pragma unroll
            for (int mi = 0; mi < 2; mi++){
                int iy = py[mi] + ky - 2, ix = px[mi] + kx - 2;
                bool ok = pok[mi] & (iy >= 0) & (iy < 7) & (ix >= 0) & (ix < 7);
                int q = ok ? iy*7 + ix : 49;             // row 49 = zeros
                aoff[mi] = q*328 + kvb + half*8;
            }
            size_t tapbase = ((size_t)(c*25 + tap))*81920;   // 40*256*8
            const short *pbh[2];
            #pragma unroll
            for (int ni = 0; ni < 2; ni++){
                int co = nq*64 + ni*32 + l31;
                pbh[ni] = w1h + tapbase + ((size_t)((kv*20 + half)*256 + co))*8;
            }
            #pragma unroll 2
            for (int ks = 0; ks < 10; ks++){
                bf16x8 Ah[2], Bh[2];
                #pragma unroll
                for (int mi = 0; mi < 2; mi++)
                    Ah[mi] = *(const bf16x8*)&xh[aoff[mi] + ks*16];
                #pragma unroll
                for (int ni = 0; ni < 2; ni++)
                    Bh[ni] = *(const bf16x8*)&pbh[ni][ks*4096];
                __builtin_amdgcn_s_setprio(1);
                #pragma unroll
                for (int mi = 0; mi < 2; mi++)
                    #pragma unroll
                    for (int ni = 0; ni < 2; ni++)
                        acc[mi][ni] = __builtin_amdgcn_mfma_f32_32x32x16_bf16(Ah[mi], Bh[ni], acc[mi][ni], 0, 0, 0);
                __builtin_amdgcn_s_setprio(0);
            }
        }
        __syncthreads();   // all conv1 LDS reads complete -> region becomes f32 scratch
        // 2-way K-combine through LDS: kv=1 writes partials, kv=0 adds.
        float* scr = (float*)smem;
        const int g = s*4 + nq;                          // 8 groups x 16 KB
        if (kv){
            #pragma unroll
            for (int t4 = 0; t4 < 4; t4++){
                const int mi = t4 >> 1, ni = t4 & 1;
                #pragma unroll
                for (int rq = 0; rq < 4; rq++){
                    f32x4 v;
                    v[0] = acc[mi][ni][rq*4+0]; v[1] = acc[mi][ni][rq*4+1];
                    v[2] = acc[mi][ni][rq*4+2]; v[3] = acc[mi][ni][rq*4+3];
                    *(f32x4*)&scr[g*4096 + (t4*4 + rq)*256 + lane*4] = v;
                }
            }
        }
        __syncthreads();
        if (!kv){
            #pragma unroll
            for (int t4 = 0; t4 < 4; t4++){
                const int mi = t4 >> 1, ni = t4 & 1;
                #pragma unroll
                for (int rq = 0; rq < 4; rq++){
                    f32x4 v = *(const f32x4*)&scr[g*4096 + (t4*4 + rq)*256 + lane*4];
                    acc[mi][ni][rq*4+0] += v[0]; acc[mi][ni][rq*4+1] += v[1];
                    acc[mi][ni][rq*4+2] += v[2]; acc[mi][ni][rq*4+3] += v[3];
                }
            }
        }
        __syncthreads();   // scratch reads complete -> region becomes conv2 input
        if (!kv){
            // epilogue: BN + LReLU -> conv2-in (bf16)
            const int co = nq*64;
            float sc[2], mm[2], bb[2];
            #pragma unroll
            for (int ni = 0; ni < 2; ni++){
                int cc = co + ni*32 + l31;
                sc[ni] = G1[c*256 + cc] * rsqrtf(V1[c*256 + cc] + BNEPS);
                mm[ni] = M1[c*256 + cc];
                bb[ni] = B1[c*256 + cc];
            }
            short* yh = smem + (s*2 + 0)*13200;
            yh[49*264 + nq*64 + (lane & 31)] = 0;  yh[49*264 + nq*64 + 32 + (lane & 31)] = 0;
            #pragma unroll
            for (int mi = 0; mi < 2; mi++)
                #pragma unroll
                for (int ni = 0; ni < 2; ni++)
                    #pragma unroll
                    for (int r = 0; r < 16; r++){
                        int p = mi*32 + (r & 3) + 8*(r >> 2) + 4*half;
                        if (p < 49){
                            float y = (acc[mi][ni][r] - mm[ni])*sc[ni] + bb[ni];
                            y = (y >= 0.f) ? y : ALPHA*y;
                            int o = p*264 + co + ni*32 + l31;
                            yh[o] = f2bf(y);
                        }
                    }
        }
    }
    __syncthreads();

    // ================= conv2: 7x7x256 -> 14x14x128 (s=2, pads 3,2), parity split, 1-term =========
    {
        const int s = wid & 1, par = (wid >> 1) & 3, nh = wid >> 3;
        const int pi = par >> 1, pj = par & 1;
        const int c = binfo[2 + s];
        const short* xh = smem + (s*2 + 0)*13200;
        f32x16 acc[2][2];
        #pragma unroll
        for (int mi = 0; mi < 2; mi++)
            #pragma unroll
            for (int ni = 0; ni < 2; ni++)
                #pragma unroll
                for (int r = 0; r < 16; r++) acc[mi][ni][r] = 0.f;
        int py[2], px[2], pok[2];
        #pragma unroll
        for (int mi = 0; mi < 2; mi++){
            int p = mi*32 + l31;
            py[mi] = p/7; px[mi] = p%7; pok[mi] = (p < 49);
        }
        const int nky = pi ? 3 : 2, kyb = pi ? 0 : 1;
        const int nkx = pj ? 3 : 2, kxb = pj ? 0 : 1;
        #pragma unroll 1
        for (int ty = 0; ty < nky; ty++){
            int ky = kyb + 2*ty;
            int dy = (pi + ky - 3) / 2;
            #pragma unroll 1
            for (int tx = 0; tx < nkx; tx++){
                int kx = kxb + 2*tx;
                int dx = (pj + kx - 3) / 2;
                int tap = ky*5 + kx;
                int aoff[2];
                #pragma unroll
                for (int mi = 0; mi < 2; mi++){
                    int u = py[mi] + dy, v = px[mi] + dx;
                    bool ok = pok[mi] & (u >= 0) & (u < 7) & (v >= 0) & (v < 7);
                    int q = ok ? u*7 + v : 49;
                    aoff[mi] = q*264 + half*8;
                }
                size_t tapbase = ((size_t)(c*25 + tap))*32768;   // 32*128*8
                const short *pbh[2];
                #pragma unroll
                for (int ni = 0; ni < 2; ni++){
                    int co = nh*64 + ni*32 + l31;
                    pbh[ni] = w2h + tapbase + ((size_t)(half*128 + co))*8;
                }
                #pragma unroll 2
                for (int ks = 0; ks < 16; ks++){
                    bf16x8 Ah[2], Bh[2];
                    #pragma unroll
                    for (int mi = 0; mi < 2; mi++)
                        Ah[mi] = *(const bf16x8*)&xh[aoff[mi] + ks*16];
                    #pragma unroll
                    for (int ni = 0; ni < 2; ni++)
                        Bh[ni] = *(const bf16x8*)&pbh[ni][ks*2048];
                    __builtin_amdgcn_s_setprio(1);
                    #pragma unroll
                    for (int mi = 0; mi < 2; mi++)
                        #pragma unroll
                        for (int ni = 0; ni < 2; ni++)
                            acc[mi][ni] = __builtin_amdgcn_mfma_f32_32x32x16_bf16(Ah[mi], Bh[ni], acc[mi][ni], 0, 0, 0);
                    __builtin_amdgcn_s_setprio(0);
                }
            }
        }
        __syncthreads();   // all conv2 LDS reads complete; smem free
        float sc[2], mm[2], bb[2];
        #pragma unroll
        for (int ni = 0; ni < 2; ni++){
            int co = nh*64 + ni*32 + l31;
            sc[ni] = G2[c*128 + co] * rsqrtf(V2[c*128 + co] + BNEPS);
            mm[ni] = M2[c*128 + co];
            bb[ni] = B2[c*128 + co];
        }
        float* h2f = (float*)smem;          // 196*132
        float* wk3 = (float*)smem + 25872;  // 3200
        #pragma unroll 1
        for (int sp = 0; sp < 2; sp++){
            if (s == sp){
                #pragma unroll
                for (int mi = 0; mi < 2; mi++)
                    #pragma unroll
                    for (int ni = 0; ni < 2; ni++)
                        #pragma unroll
                        for (int r = 0; r < 16; r++){
                            int p = mi*32 + (r & 3) + 8*(r >> 2) + 4*half;
                            if (p < 49){
                                int oy = p / 7, ox = p % 7;
                                int q2 = (2*oy + pi)*14 + (2*ox + pj);
                                float y = (acc[mi][ni][r] - mm[ni])*sc[ni] + bb[ni];
                                y = (y >= 0.f) ? y : ALPHA*y;
                                h2f[q2*132 + nh*64 + ni*32 + l31] = y;
                            }
                        }
            }
            int cs = binfo[2 + sp];
            for (int i = tid; i < 3200; i += 1024) wk3[i] = K3[cs*3200 + i];
            __syncthreads();
            // conv3: 14x14x128 -> 28x28x1, s=2, pads (3,2), tanh
            int p3 = tid;
            if (p3 < 784){
                int oi = p3 / 28, oj = p3 % 28;
                float a3 = 0.f;
                #pragma unroll
                for (int ky = 0; ky < 5; ky++){
                    int t = oi + ky - 3;
                    if (t < 0 || (t & 1) || t >= 28) continue;
                    int u = t >> 1;
                    #pragma unroll
                    for (int kx = 0; kx < 5; kx++){
                        int ss2 = oj + kx - 3;
                        if (ss2 < 0 || (ss2 & 1) || ss2 >= 28) continue;
                        int v = ss2 >> 1;
                        const float* xr = &h2f[(u*14 + v)*132];
                        const float* w = &wk3[(ky*5 + kx)*128];
                        #pragma unroll
                        for (int cc = 0; cc < 32; cc++){
                            float4 xv = *(const float4*)&xr[4*cc];
                            float4 wv = *(const float4*)&w[4*cc];
                            a3 += xv.x*wv.x + xv.y*wv.y + xv.z*wv.z + xv.w*wv.w;
                        }
                    }
                }
                out[binfo[sp]*784 + p3] = tanhf(a3);
            }
            __syncthreads();   // before next sp overwrites h2f
        }
    }
}

// =======================================================================================
// Fallback path (verified R5 kernel) — used when ws_size is too small for the MFMA path.
// =======================================================================================
#define NOISE 100
#define EMB   50
#define CIN1  306
#define S1    52

template<int PH>
__device__ __forceinline__ void conv1_full(const float* __restrict__ xt1, float* __restrict__ xt2,
                                           const float* __restrict__ wbase,
                                           float sc, float mm, float bb, int co){
    constexpr int OY0 = PH ? 4 : 0;
    constexpr int NOY = PH ? 3 : 4;
    float acc[NOY*7];
    #pragma unroll
    for (int i = 0; i < NOY*7; i++) acc[i] = 0.f;
    #pragma unroll 1
    for (int ci = 0; ci < CIN1; ci++){
        float xr[49];
        #pragma unroll
        for (int r = 0; r < 12; r++) *(float4*)&xr[4*r] = *(const float4*)&xt1[ci*S1 + 4*r];
        xr[48] = xt1[ci*S1 + 48];
        const float* wci = wbase + ci*256;
        #pragma unroll
        for (int ky = 0; ky < 5; ky++)
            #pragma unroll
            for (int kx = 0; kx < 5; kx++){
                float w = wci[(ky*5 + kx)*CIN1*256];
                #pragma unroll
                for (int oy = OY0; oy < OY0 + NOY; oy++){
                    int iy = oy + ky - 2;
                    if (iy < 0 || iy >= 7) continue;
                    #pragma unroll
                    for (int ox = 0; ox < 7; ox++){
                        int ix = ox + kx - 2;
                        if (ix < 0 || ix >= 7) continue;
                        acc[(oy - OY0)*7 + ox] += xr[iy*7 + ix] * w;
                    }
                }
            }
    }
    #pragma unroll
    for (int i = 0; i < NOY*7; i++){
        float y = (acc[i] - mm)*sc + bb;
        xt2[co*S1 + OY0*7 + i] = (y >= 0.f) ? y : ALPHA*y;
    }
}

template<int Q>
__device__ __forceinline__ void conv2_full(const float* __restrict__ xt2, float* __restrict__ xt3,
                                           const float* __restrict__ wbase,
                                           float sc, float mm, float bb, int co){
    float acc[49];
    #pragma unroll
    for (int i = 0; i < 49; i++) acc[i] = 0.f;
    #pragma unroll 1
    for (int ci = 0; ci < 256; ci++){
        float xr[49];
        #pragma unroll
        for (int r = 0; r < 12; r++) *(float4*)&xr[4*r] = *(const float4*)&xt2[ci*S1 + 4*r];
        xr[48] = xt2[ci*S1 + 48];
        const float* wci = wbase + ci*128;
        #pragma unroll
        for (int ky = 0; ky < 5; ky++)
            #pragma unroll
            for (int kx = 0; kx < 5; kx++){
                float w = wci[(ky*5 + kx)*256*128];
                #pragma unroll
                for (int ii = 0; ii < 49; ii++){
                    int p2 = Q*49 + ii;
                    int i = p2 / 14, j = p2 % 14;
                    int t = i + ky - 3, s = j + kx - 3;
                    if (t < 0 || (t & 1) || t >= 14) continue;
                    if (s < 0 || (s & 1) || s >= 14) continue;
                    acc[ii] += xr[(t >> 1)*7 + (s >> 1)] * w;
                }
            }
    }
    #pragma unroll
    for (int ii = 0; ii < 49; ii++){
        int p2 = Q*49 + ii;
        float y = (acc[ii] - mm)*sc + bb;
        xt3[p2*132 + co] = (y >= 0.f) ? y : ALPHA*y;
    }
}

__global__ __launch_bounds__(512, 2)
void fused_k(const float* __restrict__ noise, const int* __restrict__ labels,
             const float* __restrict__ emb,   const float* __restrict__ Wd,
             const float* __restrict__ g1,    const float* __restrict__ b1,
             const float* __restrict__ m1,    const float* __restrict__ v1,
             const float* __restrict__ K1,
             const float* __restrict__ G1, const float* __restrict__ B1,
             const float* __restrict__ M1, const float* __restrict__ V1,
             const float* __restrict__ K2,
             const float* __restrict__ G2, const float* __restrict__ B2,
             const float* __restrict__ M2, const float* __restrict__ V2,
             const float* __restrict__ K3,
             const int* __restrict__ order,
             float* __restrict__ out){
    __shared__ __align__(16) unsigned char smem[53248 + 103488];
    __shared__ float xin[152];
    float* xt2 = (float*)smem;
    float* wk  = (float*)smem;
    float* xt1 = (float*)(smem + 53248);
    float* xt3 = (float*)(smem + 53248);

    const int tid = threadIdx.x;
    const int idx = ((blockIdx.x & 7) << 6) | (blockIdx.x >> 3);
    const int b = order[idx];
    const int c = labels[b];

    if (tid < 150)
        xin[tid] = (tid < NOISE) ? noise[b*NOISE + tid] : emb[c*EMB + (tid - NOISE)];
    __syncthreads();
    {
        const int co = tid & 255;
        const int p0 = (tid >> 8) * 24;
        float acc[25];
        #pragma unroll
        for (int i = 0; i < 25; i++) acc[i] = 0.f;
        #pragma unroll 1
        for (int k = 0; k < 150; k++){
            float x = xin[k];
            const float* wr = Wd + k*12544 + p0*256 + co;
            #pragma unroll
            for (int i = 0; i < 25; i++) acc[i] += x * wr[i*256];
        }
        #pragma unroll
        for (int i = 0; i < 25; i++){
            int j = (p0 + i)*256 + co;
            float sc = g1[j] * rsqrtf(v1[j] + BNEPS);
            float y = (acc[i] - m1[j])*sc + b1[j];
            y = (y >= 0.f) ? y : ALPHA*y;
            xt1[co*S1 + p0 + i] = y;
        }
        if (tid < EMB){
            float v = xin[NOISE + tid];
            #pragma unroll
            for (int p = 0; p < 49; p++) xt1[(256 + tid)*S1 + p] = v;
        }
    }
    __syncthreads();
    {
        const int co = tid & 255;
        const int ph = tid >> 8;
        const float* wbase = K1 + (size_t)c*25*CIN1*256 + co;
        float sc = G1[c*256 + co] * rsqrtf(V1[c*256 + co] + BNEPS);
        float mm = M1[c*256 + co], bb = B1[c*256 + co];
        if (ph == 0) conv1_full<0>(xt1, xt2, wbase, sc, mm, bb, co);
        else         conv1_full<1>(xt1, xt2, wbase, sc, mm, bb, co);
    }
    __syncthreads();
    {
        const int co = tid & 127;
        const int q  = tid >> 7;
        const float* wbase = K2 + (size_t)c*25*256*128 + co;
        float sc = G2[c*128 + co] * rsqrtf(V2[c*128 + co] + BNEPS);
        float mm = M2[c*128 + co], bb = B2[c*128 + co];
        switch (q){
            case 0: conv2_full<0>(xt2, xt3, wbase, sc, mm, bb, co); break;
            case 1: conv2_full<1>(xt2, xt3, wbase, sc, mm, bb, co); break;
            case 2: conv2_full<2>(xt2, xt3, wbase, sc, mm, bb, co); break;
            default:conv2_full<3>(xt2, xt3, wbase, sc, mm, bb, co); break;
        }
    }
    __syncthreads();
    for (int i = tid; i < 3200; i += 512) wk[i] = K3[c*3200 + i];
    __syncthreads();
    #pragma unroll 1
    for (int rep = 0; rep < 2; rep++){
        int p3 = tid + rep*512;
        if (p3 < 784){
            int i = p3 / 28, j = p3 - (p3/28)*28;
            float acc = 0.f;
            #pragma unroll
            for (int ky = 0; ky < 5; ky++){
                int t = i + ky - 3;
                if (t < 0 || (t & 1) || t >= 28) continue;
                int u = t >> 1;
                #pragma unroll
                for (int kx = 0; kx < 5; kx++){
                    int s = j + kx - 3;
                    if (s < 0 || (s & 1) || s >= 28) continue;
                    int v = s >> 1;
                    const float* xr = &xt3[(u*14 + v)*132];
                    const float* w = &wk[(ky*5 + kx)*128];
                    #pragma unroll
                    for (int cc = 0; cc < 32; cc++){
                        float4 xv = *(const float4*)&xr[4*cc];
                        float4 wv = *(const float4*)&w[4*cc];
                        acc += xv.x*wv.x + xv.y*wv.y + xv.z*wv.z + xv.w*wv.w;
                    }
                }
            }
            out[b*784 + p3] = tanhf(acc);
        }
    }
}

extern "C" void kernel_launch(void* const* d_in, const int* in_sizes, int n_in,
                              void* d_out, int out_size, void* d_ws, size_t ws_size,
                              hipStream_t stream){
    const float* noise = (const float*)d_in[0];
    const int*   labels= (const int*)  d_in[1];
    const float* emb   = (const float*)d_in[2];
    const float* Wd    = (const float*)d_in[3];
    const float* g1    = (const float*)d_in[4];
    const float* b1    = (const float*)d_in[5];
    const float* m1    = (const float*)d_in[6];
    const float* v1    = (const float*)d_in[7];
    const float* K1    = (const float*)d_in[8];
    const float* G1    = (const float*)d_in[9];
    const float* B1    = (const float*)d_in[10];
    const float* M1    = (const float*)d_in[11];
    const float* V1    = (const float*)d_in[12];
    const float* K2    = (const float*)d_in[13];
    const float* G2    = (const float*)d_in[14];
    const float* B2    = (const float*)d_in[15];
    const float* M2    = (const float*)d_in[16];
    const float* V2    = (const float*)d_in[17];
    const float* K3    = (const float*)d_in[18];
    float* outp = (float*)d_out;

    const size_t NEED = 4096 + 2*(size_t)N1*2 + 2*(size_t)N2*2 + 2*(size_t)512*49*320*2;
    int* order = (int*)d_ws;

    if (ws_size >= NEED){
        short* w1h = (short*)((char*)d_ws + 4096);
        short* w2h = w1h + N1;
        short* xgH = w2h + N2;
        aux_k <<<1 + DENSE_BLKS + PREP_BLKS, 256, 0, stream>>>(
            noise, labels, emb, Wd, g1, b1, m1, v1, K1, K2,
            w1h, w2h, xgH, order);
        main_k <<<256, 1024, 0, stream>>>(labels, order, xgH, w1h, w2h,
                                          G1, B1, M1, V1, G2, B2, M2, V2, K3, outp);
    } else {
        // fallback: verified R5 path (needs only 2 KB ws)
        sort_k <<<1, 512, 0, stream>>>(labels, order);
        fused_k<<<512, 512, 0, stream>>>(noise, labels, emb, Wd, g1, b1, m1, v1,
                                         K1, G1, B1, M1, V1,
                                         K2, G2, B2, M2, V2, K3, order, outp);
    }
}